// Round 4
// baseline (49772.968 us; speedup 1.0000x reference)
//
#include <hip/hip_runtime.h>
#include <hip/hip_bf16.h>
#include <math.h>

#define BB 32
#define T_INC 12
#define T_OUTC 12
#define NN 200
#define DIN0 2
#define HH 128
#define DHALF 64
#define NB (NN*BB)
#define XROW 256                      // fixed row stride (elems) for all X arrays
#define MSTRIDE ((size_t)NB*XROW)     // per-m stride in elems
#define INV_SQRT_H 0.08838834764831845f

typedef __attribute__((ext_vector_type(8))) short bf16x8;
typedef __attribute__((ext_vector_type(4))) float f32x4;

__device__ __forceinline__ float sigmf(float x){ return 1.f/(1.f+expf(-x)); }
__device__ __forceinline__ float bfu(uint32_t b){ union{uint32_t u;float f;}v; v.u=b<<16; return v.f; }
__device__ __forceinline__ uint32_t fbf(float f){ union{float f2;uint32_t u;}v; v.f2=f; return (v.u + 0x7fffu + ((v.u>>16)&1u))>>16; }
// split v into bf16 hi + bf16 lo (v ~= hi + lo to ~16 mantissa bits)
__device__ __forceinline__ void splitbf(float v, uint32_t& hi, uint32_t& lo){
  hi = fbf(v);
  lo = fbf(v - bfu(hi));
}

// ---------------- prep: transpose Whh (3H x H) -> (H x 3H) ----------------
__global__ void k_whhT(const float* __restrict__ Whh, float* __restrict__ WT) {
  int idx = blockIdx.x*256 + threadIdx.x;
  if (idx >= 3*HH*HH) return;
  int i3 = idx / HH; int k = idx % HH;
  WT[(size_t)k*(3*HH) + i3] = Whh[idx];
}

// ---------------- prep: shuffle dense weights into MFMA B-fragment layout, hi/lo ----
__global__ void k_wshuf(const float* __restrict__ W, __hip_bfloat16* __restrict__ Wfh,
                        __hip_bfloat16* __restrict__ Wfl, int d, int d_pad, int OUT) {
  int idx = blockIdx.x*256 + threadIdx.x;
  int total = 5*d_pad*OUT;
  if (idx >= total) return;
  int o = idx % OUT; int tmp = idx / OUT; int k = tmp % d_pad; int m = tmp / d_pad;
  float v = (k < d) ? W[((size_t)k*5 + m)*OUT + o] : 0.f;
  int kt = k >> 5, kr = k & 31;
  int lane = ((kr>>3)<<4) | (o & 15);
  int j = kr & 7;
  int nt = o >> 4;
  int KT = d_pad >> 5, NT = OUT >> 4;
  size_t addr = ((((size_t)m*KT + kt)*NT + nt)*64 + (size_t)lane)*8 + j;
  uint32_t hi, lo; splitbf(v, hi, lo);
  Wfh[addr] = *(__hip_bfloat16*)&hi;
  Wfl[addr] = *(__hip_bfloat16*)&lo;
}

// ---------------- GRU step (WhhT coalesced) ----------------
__global__ __launch_bounds__(512) void k_gru_step(
    const float* __restrict__ enc_in, const float* __restrict__ Wih,
    const float* __restrict__ WhhT, const float* __restrict__ bih,
    const float* __restrict__ bhh, float* __restrict__ h,
    float* __restrict__ outs, int t) {
  int row0 = blockIdx.x * 4;
  int tid = threadIdx.x;
  int rr = tid >> 7;
  int i = tid & 127;
  int row = row0 + rr;
  int n = row / BB, b = row % BB;
  __shared__ float hs[4][HH];
  hs[rr][i] = h[(size_t)row*HH + i];
  __syncthreads();
  float x0 = enc_in[(((size_t)b*T_INC + t)*NN + n)*DIN0 + 0];
  float x1 = enc_in[(((size_t)b*T_INC + t)*NN + n)*DIN0 + 1];
  float ir = Wih[(0*HH+i)*2+0]*x0 + Wih[(0*HH+i)*2+1]*x1 + bih[0*HH+i];
  float iz = Wih[(1*HH+i)*2+0]*x0 + Wih[(1*HH+i)*2+1]*x1 + bih[1*HH+i];
  float ig = Wih[(2*HH+i)*2+0]*x0 + Wih[(2*HH+i)*2+1]*x1 + bih[2*HH+i];
  float hr = bhh[i], hz = bhh[HH+i], hg = bhh[2*HH+i];
  for (int k=0;k<HH;k++) {
    float hv = hs[rr][k];
    const float* wr = WhhT + (size_t)k*(3*HH);
    hr += wr[i]*hv; hz += wr[i+128]*hv; hg += wr[i+256]*hv;
  }
  float r = sigmf(ir+hr);
  float z = sigmf(iz+hz);
  float nn2 = tanhf(ig + r*hg);
  float hn = (1.f-z)*nn2 + z*hs[rr][i];
  h[(size_t)row*HH+i] = hn;
  outs[(((size_t)t*NN+n)*BB+b)*HH + i] = hn;
}

// ---------------- length-attention pooling ----------------
__global__ void k_att_pool(const float* __restrict__ outs, const float* __restrict__ attW,
                           const float* __restrict__ attb, const float* __restrict__ wlc,
                           float* __restrict__ pooled) {
  int row = blockIdx.x; int n = row / BB, b = row % BB;
  int lane = threadIdx.x; // 64
  __shared__ float o_s[T_INC][HH];
  for (int t=0;t<T_INC;t++)
    for (int k=lane;k<HH;k+=64)
      o_s[t][k] = outs[(((size_t)t*NN+n)*BB+b)*HH + k];
  __syncthreads();
  float wc = wlc[lane];
  float ab = attb[lane];
  float logit[T_INC];
  for (int t=0;t<T_INC;t++) {
    float acc = ab;
    const float* wr = attW + (size_t)lane*HH;
    for (int k=0;k<HH;k++) acc += wr[k]*o_s[t][k];
    logit[t] = fmaxf(acc, 0.f)*wc;
  }
  for (int off=32; off; off>>=1)
    for (int t=0;t<T_INC;t++) logit[t] += __shfl_xor(logit[t], off, 64);
  float mx = -1e30f;
  for (int t=0;t<T_INC;t++) mx = fmaxf(mx, logit[t]);
  float s = 0.f;
  for (int t=0;t<T_INC;t++) { logit[t] = expf(logit[t]-mx); s += logit[t]; }
  float inv = 1.f/s;
  for (int k=lane;k<HH;k+=64) {
    float acc = 0.f;
    for (int t=0;t<T_INC;t++) acc += o_s[t][k]*logit[t];
    pooled[((size_t)b*NN+n)*HH + k] = acc*inv;
  }
}

// ---------------- key/query projections ----------------
__global__ void k_keyquery(const float* __restrict__ pooled, const float* __restrict__ wkey,
                           const float* __restrict__ wqry, float* __restrict__ keym,
                           float* __restrict__ qm) {
  int bn = blockIdx.x; int lane = threadIdx.x; // 64
  __shared__ float p_s[HH];
  p_s[lane] = pooled[(size_t)bn*HH + lane];
  p_s[lane+64] = pooled[(size_t)bn*HH + lane + 64];
  __syncthreads();
  float ka = 0.f, qa = 0.f;
  for (int k=0;k<HH;k++) {
    float pv = p_s[k];
    ka += pv*wkey[(size_t)k*DHALF + lane];
    qa += pv*wqry[(size_t)k*DHALF + lane];
  }
  keym[(size_t)bn*DHALF + lane] = ka;
  qm[(size_t)bn*DHALF + lane] = qa;
}

// ---------------- attention row -> softmax -> topk -> adj row + rowsum ----------------
__global__ void k_attn_row(const float* __restrict__ keym, const float* __restrict__ qm,
                           const int* __restrict__ topkp, float* __restrict__ adj,
                           float* __restrict__ rowsum) {
  int bn = blockIdx.x; int b = bn / NN; int n = bn % NN;
  int tid = threadIdx.x; // 256
  __shared__ float key_s[DHALF];
  __shared__ float attv[256];
  __shared__ float red[256];
  __shared__ int redi[256];
  if (tid < DHALF) key_s[tid] = keym[(size_t)bn*DHALF + tid];
  __syncthreads();
  float sc = -1e30f;
  if (tid < NN) {
    float a = 0.f;
    const float* qrow = qm + ((size_t)b*NN + tid)*DHALF;
    for (int k=0;k<DHALF;k++) a += key_s[k]*qrow[k];
    sc = a * INV_SQRT_H;
  }
  red[tid] = sc; __syncthreads();
  for (int s=128;s>0;s>>=1){ if (tid<s) red[tid]=fmaxf(red[tid],red[tid+s]); __syncthreads(); }
  float mx = red[0]; __syncthreads();
  float e = (tid<NN) ? expf(sc-mx) : 0.f;
  red[tid] = e; __syncthreads();
  for (int s=128;s>0;s>>=1){ if (tid<s) red[tid]+=red[tid+s]; __syncthreads(); }
  float inv = 1.f/red[0]; __syncthreads();
  float av = e*inv;
  attv[tid] = (tid<NN) ? av : -1e30f;
  __syncthreads();
  int Ks = topkp[0]; if (Ks > NN) Ks = NN;
  float kth = -1e30f;
  for (int it=0; it<Ks; it++) {
    red[tid] = attv[tid]; redi[tid] = tid; __syncthreads();
    for (int s=128;s>0;s>>=1){
      if (tid<s && red[tid+s] > red[tid]) { red[tid]=red[tid+s]; redi[tid]=redi[tid+s]; }
      __syncthreads();
    }
    kth = red[0];
    if (tid==0) attv[redi[0]] = -1e30f;
    __syncthreads();
  }
  float aout = 0.f;
  if (tid < NN) {
    aout = (av >= kth) ? av : 0.f;
    if (tid == n) aout += 1.f;
    adj[((size_t)b*NN+n)*NN + tid] = aout;
  }
  red[tid] = aout; __syncthreads();
  for (int s=128;s>0;s>>=1){ if (tid<s) red[tid]+=red[tid+s]; __syncthreads(); }
  if (tid==0) rowsum[bn] = red[0];
}

// ---------------- column sums of adj ----------------
__global__ void k_colsum(const float* __restrict__ adj, float* __restrict__ cs) {
  int b = blockIdx.x;
  for (int j=threadIdx.x; j<NN; j+=blockDim.x) {
    float s = 0.f;
    for (int i=0;i<NN;i++) s += adj[((size_t)b*NN+i)*NN + j];
    cs[(size_t)b*NN + j] = s;
  }
}

// ---------------- build sparse gather lists (deterministic) ----------------
__global__ void k_sparsify(const float* __restrict__ adj, const float* __restrict__ rs,
                           const float* __restrict__ cs,
                           int* __restrict__ s2cnt, int* __restrict__ s2col, float* __restrict__ s2val,
                           int* __restrict__ s1cnt, int* __restrict__ s1col, float* __restrict__ s1val) {
  int bn = blockIdx.x; int b = bn/NN; int i = bn%NN;
  int lane = threadIdx.x; // 64
  int cnt = 0;
  for (int j0=0;j0<NN;j0+=64) {
    int j = j0+lane;
    float v = (j<NN) ? adj[((size_t)b*NN+i)*NN + j] : 0.f;
    bool nz = (v != 0.f);
    unsigned long long m = __ballot(nz);
    int pos = cnt + __popcll(m & ((1ull<<lane)-1ull));
    if (nz) { s2col[(size_t)bn*NN+pos] = j; s2val[(size_t)bn*NN+pos] = v / cs[(size_t)b*NN+j]; }
    cnt += __popcll(m);
  }
  if (lane==0) s2cnt[bn] = cnt;
  cnt = 0;
  for (int j0=0;j0<NN;j0+=64) {
    int j = j0+lane;
    float v = (j<NN) ? adj[((size_t)b*NN+j)*NN + i] : 0.f;
    bool nz = (v != 0.f);
    unsigned long long m = __ballot(nz);
    int pos = cnt + __popcll(m & ((1ull<<lane)-1ull));
    if (nz) { s1col[(size_t)bn*NN+pos] = j; s1val[(size_t)bn*NN+pos] = v / rs[(size_t)b*NN+j]; }
    cnt += __popcll(m);
  }
  if (lane==0) s1cnt[bn] = cnt;
}

// ---------------- concat -> fp32 x0f + bf16 hi/lo shadows ----------------
__global__ void k_concat_tri(const float* __restrict__ x, int bs, int ns, int din,
                             const float* __restrict__ h, const float* __restrict__ ru,
                             float* __restrict__ x0f,
                             __hip_bfloat16* __restrict__ x0h, __hip_bfloat16* __restrict__ x0l,
                             int d, int d_pad) {
  int idx = blockIdx.x*256 + threadIdx.x;
  if (idx >= NB*d_pad) return;
  int row = idx / d_pad; int c = idx % d_pad;
  int b = row / NN, n = row % NN;
  float v = 0.f;
  if (c < din) {
    v = x[(size_t)b*bs + (size_t)n*ns + c];
  } else if (c < d) {
    int k = c - din;
    v = h[(size_t)row*HH + k];
    if (ru) v *= ru[(size_t)row*256 + k];
  }
  size_t a = (size_t)row*XROW + c;
  x0f[a] = v;
  uint32_t hi, lo; splitbf(v, hi, lo);
  x0h[a] = *(__hip_bfloat16*)&hi;
  x0l[a] = *(__hip_bfloat16*)&lo;
}

// ---------------- dual-support fp32 SpMM; fp32 out + hi/lo shadows -------------------
__global__ __launch_bounds__(256) void k_spmm2(
    const int* __restrict__ cnt1, const int* __restrict__ col1, const float* __restrict__ val1,
    const int* __restrict__ cnt2, const int* __restrict__ col2, const float* __restrict__ val2,
    const float* __restrict__ Xin1, const float* __restrict__ Xin2,
    const float* __restrict__ X0c,
    float* __restrict__ out1, float* __restrict__ out2,
    __hip_bfloat16* __restrict__ oh1, __hip_bfloat16* __restrict__ oh2,
    __hip_bfloat16* __restrict__ ol1, __hip_bfloat16* __restrict__ ol2,
    int d_pad) {
  int b = blockIdx.y; int r0 = blockIdx.x*8;
  int tid = threadIdx.x;
  int half = d_pad >> 1;            // float2 per output row per thread
  if (tid >= 2*half) return;
  int side = (tid >= half) ? 1 : 0;
  int t = side ? tid - half : tid;
  const int* cntp = side ? cnt2 : cnt1;
  const int* colp = side ? col2 : col1;
  const float* valp = side ? val2 : val1;
  const float* Xin = side ? Xin2 : Xin1;
  float* outp = side ? out2 : out1;
  __hip_bfloat16* ohp = side ? oh2 : oh1;
  __hip_bfloat16* olp = side ? ol2 : ol1;
  int cc = t*2;
  for (int r=0;r<8;r++) {
    int bn = b*NN + r0 + r;
    int cn = cntp[bn];
    size_t lbase = (size_t)bn*NN;
    float a0=0.f, a1=0.f;
    for (int k=0;k<cn;k++) {
      int cj = colp[lbase+k];
      float vv = valp[lbase+k];
      const float2 xv = *(const float2*)(Xin + ((size_t)(b*NN+cj))*XROW + cc);
      a0 += vv*xv.x; a1 += vv*xv.y;
    }
    if (X0c) {
      const float2 x0 = *(const float2*)(X0c + (size_t)bn*XROW + cc);
      a0 = 2.f*a0 - x0.x; a1 = 2.f*a1 - x0.y;
    }
    size_t oa = (size_t)bn*XROW + cc;
    *(float2*)(outp + oa) = make_float2(a0, a1);
    uint32_t h0,l0,h1,l1; splitbf(a0,h0,l0); splitbf(a1,h1,l1);
    *(uint32_t*)(ohp + oa) = h0 | (h1 << 16);
    *(uint32_t*)(olp + oa) = l0 | (l1 << 16);
  }
}

// ---------------- dense via split-bf16 MFMA: Y = act( sum_m Xm @ Wm + b ) ------------
// A*W ~= Ah*Wh + Al*Wh + Ah*Wl  (3 MFMAs, fp32-grade)
// PATH 0 (gate):   RU[row*256+col] = sigmoid(v)        (OUT=256)
// PATH 1 (cand):   hnew[row*128+col] = u*h + (1-u)*tanh(v), u = RU[row*256+128+col]
template<int OUT, int PATH>
__global__ __launch_bounds__(256) void k_dense_mfma(
    const __hip_bfloat16* __restrict__ Xh, const __hip_bfloat16* __restrict__ Xl,
    const __hip_bfloat16* __restrict__ Wfh, const __hip_bfloat16* __restrict__ Wfl,
    const float* __restrict__ bias, int d_pad,
    float* __restrict__ RU, const float* __restrict__ h, float* __restrict__ hnew) {
  int tid = threadIdx.x;
  int w = tid >> 6, l = tid & 63;
  int rbase = blockIdx.x*32 + (w&1)*16;
  int cbase = blockIdx.y*128 + (w>>1)*64;
  const int NT = OUT >> 4;
  int KT = d_pad >> 5;
  f32x4 acc[4];
  #pragma unroll
  for (int q=0;q<4;q++) acc[q] = (f32x4){0.f,0.f,0.f,0.f};
  int arow = rbase + (l & 15);
  int akoff = (l >> 4) * 8;
  size_t aoff = (size_t)arow*XROW + akoff;
  size_t boff = (((size_t)(cbase>>4))*64 + l)*8;
  for (int m=0;m<5;m++) {
    for (int kt=0; kt<KT; kt++) {
      size_t ao = aoff + (size_t)m*MSTRIDE + kt*32;
      bf16x8 ah = *(const bf16x8*)(Xh + ao);
      bf16x8 al = *(const bf16x8*)(Xl + ao);
      size_t bo = boff + ((size_t)(m*KT + kt)*NT)*64*8;
      #pragma unroll
      for (int q=0;q<4;q++) {
        bf16x8 bh = *(const bf16x8*)(Wfh + bo + (size_t)q*64*8);
        bf16x8 bl = *(const bf16x8*)(Wfl + bo + (size_t)q*64*8);
        acc[q] = __builtin_amdgcn_mfma_f32_16x16x32_bf16(ah, bl, acc[q], 0, 0, 0);
        acc[q] = __builtin_amdgcn_mfma_f32_16x16x32_bf16(al, bh, acc[q], 0, 0, 0);
        acc[q] = __builtin_amdgcn_mfma_f32_16x16x32_bf16(ah, bh, acc[q], 0, 0, 0);
      }
    }
  }
  int drow0 = rbase + ((l>>4)<<2);
  int col0 = l & 15;
  #pragma unroll
  for (int q=0;q<4;q++) {
    int col = cbase + q*16 + col0;
    float bv = bias[col];
    #pragma unroll
    for (int r=0;r<4;r++) {
      int row = drow0 + r;
      float v = acc[q][r] + bv;
      if (PATH==0) {
        RU[(size_t)row*256 + col] = sigmf(v);
      } else {
        float c = tanhf(v);
        float u = RU[(size_t)row*256 + 128 + col];
        hnew[(size_t)row*HH + col] = u*h[(size_t)row*HH + col] + (1.f-u)*c;
      }
    }
  }
}

// ---------------- projection + output + next decoder input ----------------
__global__ void k_proj(const float* __restrict__ h, const float* __restrict__ pW,
                       const float* __restrict__ pb, float* __restrict__ out,
                       float* __restrict__ decx, int t) {
  int row = blockIdx.x; int lane = threadIdx.x; // 64
  const float* hr = h + (size_t)row*HH;
  float v = hr[lane]*pW[lane] + hr[lane+64]*pW[lane+64];
  for (int off=32; off; off>>=1) v += __shfl_xor(v, off, 64);
  if (lane==0) {
    float pv = v + pb[0];
    out[(size_t)t*BB*NN + row] = pv;
    decx[row] = pv;
  }
}

extern "C" void kernel_launch(void* const* d_in, const int* in_sizes, int n_in,
                              void* d_out, int out_size, void* d_ws, size_t ws_size,
                              hipStream_t stream) {
  const float* enc_in = (const float*)d_in[0];
  const float* gWih = (const float*)d_in[2];
  const float* gWhh = (const float*)d_in[3];
  const float* gbih = (const float*)d_in[4];
  const float* gbhh = (const float*)d_in[5];
  const float* attW = (const float*)d_in[6];
  const float* attb = (const float*)d_in[7];
  const float* wlc  = (const float*)d_in[8];
  const float* wkey = (const float*)d_in[9];
  const float* wqry = (const float*)d_in[10];
  const float* cWg[4] = {(const float*)d_in[11],(const float*)d_in[15],(const float*)d_in[19],(const float*)d_in[23]};
  const float* cbg[4] = {(const float*)d_in[12],(const float*)d_in[16],(const float*)d_in[20],(const float*)d_in[24]};
  const float* cWc[4] = {(const float*)d_in[13],(const float*)d_in[17],(const float*)d_in[21],(const float*)d_in[25]};
  const float* cbc[4] = {(const float*)d_in[14],(const float*)d_in[18],(const float*)d_in[22],(const float*)d_in[26]};
  const float* pW = (const float*)d_in[27];
  const float* pb = (const float*)d_in[28];
  const int* topkp = (const int*)d_in[29];
  float* out = (float*)d_out;

  // d_pad per param set: 0=enc l0 (d=130), 1=enc l1 (256), 2=dec l0 (129), 3=dec l1 (256)
  const int d_full[4] = {130, 256, 129, 256};
  const int d_padv[4] = {160, 256, 160, 256};

  float* ws = (float*)d_ws;
  size_t off = 0;
  auto alloc = [&](size_t n) { float* p = ws + off; off += (n + 255) & ~(size_t)255; return p; };

  // ---- persistent allocations ----
  float* RS   = alloc(NB);
  float* CS   = alloc(NB);
  int*   S2CNT= (int*)alloc(NB);
  int*   S1CNT= (int*)alloc(NB);
  int*   S2COL= (int*)alloc((size_t)NB*NN);
  float* S2VAL= alloc((size_t)NB*NN);
  int*   S1COL= (int*)alloc((size_t)NB*NN);
  float* S1VAL= alloc((size_t)NB*NN);
  float* RU   = alloc((size_t)NB*256);
  float* H0A  = alloc((size_t)NB*HH);
  float* H0B  = alloc((size_t)NB*HH);
  float* H1A  = alloc((size_t)NB*HH);
  float* H1B  = alloc((size_t)NB*HH);
  float* DECX = alloc(NB);
  float* WHHT = alloc((size_t)3*HH*HH);
  __hip_bfloat16 *WGFh[4], *WGFl[4], *WCFh[4], *WCFl[4];
  for (int p=0;p<4;p++) {
    WGFh[p] = (__hip_bfloat16*)alloc((size_t)5*d_padv[p]*256/2);
    WGFl[p] = (__hip_bfloat16*)alloc((size_t)5*d_padv[p]*256/2);
    WCFh[p] = (__hip_bfloat16*)alloc((size_t)5*d_padv[p]*128/2);
    WCFl[p] = (__hip_bfloat16*)alloc((size_t)5*d_padv[p]*128/2);
  }

  // ---- union region: supports-phase scratch OR cell-phase X arrays ----
  const size_t SUP_SZ = (size_t)T_INC*NN*BB*HH   // OUTS
                      + (size_t)NB*HH            // HGRU
                      + (size_t)NB*HH            // POOL
                      + (size_t)NB*DHALF*2       // KEYM,QMM
                      + (size_t)BB*NN*NN + 4096; // ADJ + pad
  const size_t CELL_SZ = 5*MSTRIDE + 5*MSTRIDE/2 + 5*MSTRIDE/2 + 4096; // XF + XH + XL
  float* UNION = alloc(SUP_SZ > CELL_SZ ? SUP_SZ : CELL_SZ);
  // supports view
  float* OUTS = UNION;
  float* HGRU = OUTS + (size_t)T_INC*NN*BB*HH;
  float* POOL = HGRU + (size_t)NB*HH;
  float* KEYM = POOL + (size_t)NB*HH;
  float* QMM  = KEYM + (size_t)NB*DHALF;
  float* ADJ  = QMM  + (size_t)NB*DHALF;
  // cells view
  float* XF = UNION;                                           // 5 fp32 arrays
  __hip_bfloat16* XH = (__hip_bfloat16*)(UNION + 5*MSTRIDE);   // 5 bf16 hi arrays
  __hip_bfloat16* XL = (__hip_bfloat16*)(UNION + 5*MSTRIDE + 5*MSTRIDE/2);

  if (off*sizeof(float) > ws_size) return;

  hipMemsetAsync(HGRU, 0, (size_t)NB*HH*sizeof(float), stream);
  hipMemsetAsync(H0A, 0, (size_t)NB*HH*sizeof(float), stream);
  hipMemsetAsync(H1A, 0, (size_t)NB*HH*sizeof(float), stream);
  hipMemsetAsync(DECX, 0, (size_t)NB*sizeof(float), stream);

  // ---- prep: weight transforms ----
  k_whhT<<<(3*HH*HH+255)/256, 256, 0, stream>>>(gWhh, WHHT);
  for (int p=0;p<4;p++) {
    int tg = 5*d_padv[p]*256;
    k_wshuf<<<(tg+255)/256, 256, 0, stream>>>(cWg[p], WGFh[p], WGFl[p], d_full[p], d_padv[p], 256);
    int tc = 5*d_padv[p]*128;
    k_wshuf<<<(tc+255)/256, 256, 0, stream>>>(cWc[p], WCFh[p], WCFl[p], d_full[p], d_padv[p], 128);
  }

  // ---- supports ----
  for (int t=0;t<T_INC;t++)
    k_gru_step<<<NB/4, 512, 0, stream>>>(enc_in, gWih, WHHT, gbih, gbhh, HGRU, OUTS, t);
  k_att_pool<<<NB, 64, 0, stream>>>(OUTS, attW, attb, wlc, POOL);
  k_keyquery<<<NB, 64, 0, stream>>>(POOL, wkey, wqry, KEYM, QMM);
  k_attn_row<<<NB, 256, 0, stream>>>(KEYM, QMM, topkp, ADJ, RS);
  k_colsum<<<BB, 256, 0, stream>>>(ADJ, CS);
  k_sparsify<<<NB, 64, 0, stream>>>(ADJ, RS, CS, S2CNT, S2COL, S2VAL, S1CNT, S1COL, S1VAL);

  float* X0f = XF;              float* X1f = XF + 1*MSTRIDE;
  float* X2f = XF + 2*MSTRIDE;  float* X3f = XF + 3*MSTRIDE;
  float* X4f = XF + 4*MSTRIDE;
  __hip_bfloat16 *X0h = XH,           *X1h = XH + 1*MSTRIDE, *X2h = XH + 2*MSTRIDE,
                 *X3h = XH + 3*MSTRIDE, *X4h = XH + 4*MSTRIDE;
  __hip_bfloat16 *X0l = XL,           *X1l = XL + 1*MSTRIDE, *X2l = XL + 2*MSTRIDE,
                 *X3l = XL + 3*MSTRIDE, *X4l = XL + 4*MSTRIDE;

  auto gconv = [&](const float* x, int bs, int ns, int din, const float* hcur,
                   const float* ru, int pidx) {
    int d = d_full[pidx], dp = d_padv[pidx];
    dim3 cg((unsigned)((NB*dp + 255)/256));
    dim3 sg(NN/8, BB);
    k_concat_tri<<<cg,256,0,stream>>>(x, bs, ns, din, hcur, ru, X0f, X0h, X0l, d, dp);
    k_spmm2<<<sg,256,0,stream>>>(S1CNT,S1COL,S1VAL, S2CNT,S2COL,S2VAL,
                                 X0f, X0f, nullptr, X1f, X3f, X1h, X3h, X1l, X3l, dp);
    k_spmm2<<<sg,256,0,stream>>>(S1CNT,S1COL,S1VAL, S2CNT,S2COL,S2VAL,
                                 X1f, X3f, X0f, X2f, X4f, X2h, X4h, X2l, X4l, dp);
  };

  auto cell = [&](const float* x, int bs, int ns, int din,
                  float** hcur, float** halt, int pidx) {
    int dp = d_padv[pidx];
    // gate
    gconv(x, bs, ns, din, *hcur, nullptr, pidx);
    k_dense_mfma<256,0><<<dim3(NB/32,2),256,0,stream>>>(XH, XL, WGFh[pidx], WGFl[pidx],
                                                        cbg[pidx], dp, RU, nullptr, nullptr);
    // candidate (+fused hnew)
    gconv(x, bs, ns, din, *hcur, RU, pidx);
    k_dense_mfma<128,1><<<dim3(NB/32,1),256,0,stream>>>(XH, XL, WCFh[pidx], WCFl[pidx],
                                                        cbc[pidx], dp, RU, *hcur, *halt);
    float* tswp = *hcur; *hcur = *halt; *halt = tswp;
  };

  float* h0cur = H0A; float* h0alt = H0B;
  float* h1cur = H1A; float* h1alt = H1B;

  for (int t=0;t<T_INC;t++) {
    cell(enc_in + (size_t)t*NN*DIN0, T_INC*NN*DIN0, DIN0, DIN0, &h0cur, &h0alt, 0);
    cell(h0cur, NN*HH, HH, HH, &h1cur, &h1alt, 1);
  }
  for (int t=0;t<T_OUTC;t++) {
    cell(DECX, NN, 1, 1, &h0cur, &h0alt, 2);
    cell(h0cur, NN*HH, HH, HH, &h1cur, &h1alt, 3);
    k_proj<<<NB,64,0,stream>>>(h1cur, pW, pb, out, DECX, t);
  }
}

// Round 6
// 35153.973 us; speedup vs baseline: 1.4159x; 1.4159x over previous
//
#include <hip/hip_runtime.h>
#include <hip/hip_bf16.h>
#include <math.h>

#define BB 32
#define T_INC 12
#define T_OUTC 12
#define NN 200
#define DIN0 2
#define HH 128
#define DHALF 64
#define NB (NN*BB)
#define XROW 256                      // fixed row stride (elems) for X planes
#define MSTRIDE ((size_t)NB*XROW)     // per-m stride in elems
#define CHUNK 64                      // column chunk per gconv block
#define GCONV_LDS (2*NN*CHUNK*4)      // two fp32 panels = 102,400 B
#define INV_SQRT_H 0.08838834764831845f

typedef __attribute__((ext_vector_type(8))) short bf16x8;
typedef __attribute__((ext_vector_type(4))) float f32x4;

__device__ __forceinline__ float sigmf(float x){ return 1.f/(1.f+expf(-x)); }
__device__ __forceinline__ float bfu(uint32_t b){ union{uint32_t u;float f;}v; v.u=b<<16; return v.f; }
__device__ __forceinline__ uint32_t fbf(float f){ union{float f2;uint32_t u;}v; v.f2=f; return (v.u + 0x7fffu + ((v.u>>16)&1u))>>16; }
// split v into bf16 hi + bf16 lo (v ~= hi + lo to ~17 mantissa bits)
__device__ __forceinline__ void splitbf(float v, uint32_t& hi, uint32_t& lo){
  hi = fbf(v);
  lo = fbf(v - bfu(hi));
}

// ---------------- prep: transpose Whh (3H x H) -> (H x 3H) ----------------
__global__ void k_whhT(const float* __restrict__ Whh, float* __restrict__ WT) {
  int idx = blockIdx.x*256 + threadIdx.x;
  if (idx >= 3*HH*HH) return;
  int i3 = idx / HH; int k = idx % HH;
  WT[(size_t)k*(3*HH) + i3] = Whh[idx];
}

// ---------------- prep: shuffle dense weights into MFMA B-fragment layout, hi/lo ----
__global__ void k_wshuf(const float* __restrict__ W, __hip_bfloat16* __restrict__ Wfh,
                        __hip_bfloat16* __restrict__ Wfl, int d, int d_pad, int OUT) {
  int idx = blockIdx.x*256 + threadIdx.x;
  int total = 5*d_pad*OUT;
  if (idx >= total) return;
  int o = idx % OUT; int tmp = idx / OUT; int k = tmp % d_pad; int m = tmp / d_pad;
  float v = (k < d) ? W[((size_t)k*5 + m)*OUT + o] : 0.f;
  int kt = k >> 5, kr = k & 31;
  int lane = ((kr>>3)<<4) | (o & 15);
  int j = kr & 7;
  int nt = o >> 4;
  int KT = d_pad >> 5, NT = OUT >> 4;
  size_t addr = ((((size_t)m*KT + kt)*NT + nt)*64 + (size_t)lane)*8 + j;
  uint32_t hi, lo; splitbf(v, hi, lo);
  Wfh[addr] = *(__hip_bfloat16*)&hi;
  Wfl[addr] = *(__hip_bfloat16*)&lo;
}

// ---------------- GRU step (WhhT coalesced) ----------------
__global__ __launch_bounds__(512) void k_gru_step(
    const float* __restrict__ enc_in, const float* __restrict__ Wih,
    const float* __restrict__ WhhT, const float* __restrict__ bih,
    const float* __restrict__ bhh, float* __restrict__ h,
    float* __restrict__ outs, int t) {
  int row0 = blockIdx.x * 4;
  int tid = threadIdx.x;
  int rr = tid >> 7;
  int i = tid & 127;
  int row = row0 + rr;
  int n = row / BB, b = row % BB;
  __shared__ float hs[4][HH];
  hs[rr][i] = h[(size_t)row*HH + i];
  __syncthreads();
  float x0 = enc_in[(((size_t)b*T_INC + t)*NN + n)*DIN0 + 0];
  float x1 = enc_in[(((size_t)b*T_INC + t)*NN + n)*DIN0 + 1];
  float ir = Wih[(0*HH+i)*2+0]*x0 + Wih[(0*HH+i)*2+1]*x1 + bih[0*HH+i];
  float iz = Wih[(1*HH+i)*2+0]*x0 + Wih[(1*HH+i)*2+1]*x1 + bih[1*HH+i];
  float ig = Wih[(2*HH+i)*2+0]*x0 + Wih[(2*HH+i)*2+1]*x1 + bih[2*HH+i];
  float hr = bhh[i], hz = bhh[HH+i], hg = bhh[2*HH+i];
  for (int k=0;k<HH;k++) {
    float hv = hs[rr][k];
    const float* wr = WhhT + (size_t)k*(3*HH);
    hr += wr[i]*hv; hz += wr[i+128]*hv; hg += wr[i+256]*hv;
  }
  float r = sigmf(ir+hr);
  float z = sigmf(iz+hz);
  float nn2 = tanhf(ig + r*hg);
  float hn = (1.f-z)*nn2 + z*hs[rr][i];
  h[(size_t)row*HH+i] = hn;
  outs[(((size_t)t*NN+n)*BB+b)*HH + i] = hn;
}

// ---------------- length-attention pooling ----------------
__global__ void k_att_pool(const float* __restrict__ outs, const float* __restrict__ attW,
                           const float* __restrict__ attb, const float* __restrict__ wlc,
                           float* __restrict__ pooled) {
  int row = blockIdx.x; int n = row / BB, b = row % BB;
  int lane = threadIdx.x; // 64
  __shared__ float o_s[T_INC][HH];
  for (int t=0;t<T_INC;t++)
    for (int k=lane;k<HH;k+=64)
      o_s[t][k] = outs[(((size_t)t*NN+n)*BB+b)*HH + k];
  __syncthreads();
  float wc = wlc[lane];
  float ab = attb[lane];
  float logit[T_INC];
  for (int t=0;t<T_INC;t++) {
    float acc = ab;
    const float* wr = attW + (size_t)lane*HH;
    for (int k=0;k<HH;k++) acc += wr[k]*o_s[t][k];
    logit[t] = fmaxf(acc, 0.f)*wc;
  }
  for (int off=32; off; off>>=1)
    for (int t=0;t<T_INC;t++) logit[t] += __shfl_xor(logit[t], off, 64);
  float mx = -1e30f;
  for (int t=0;t<T_INC;t++) mx = fmaxf(mx, logit[t]);
  float s = 0.f;
  for (int t=0;t<T_INC;t++) { logit[t] = expf(logit[t]-mx); s += logit[t]; }
  float inv = 1.f/s;
  for (int k=lane;k<HH;k+=64) {
    float acc = 0.f;
    for (int t=0;t<T_INC;t++) acc += o_s[t][k]*logit[t];
    pooled[((size_t)b*NN+n)*HH + k] = acc*inv;
  }
}

// ---------------- key/query projections ----------------
__global__ void k_keyquery(const float* __restrict__ pooled, const float* __restrict__ wkey,
                           const float* __restrict__ wqry, float* __restrict__ keym,
                           float* __restrict__ qm) {
  int bn = blockIdx.x; int lane = threadIdx.x; // 64
  __shared__ float p_s[HH];
  p_s[lane] = pooled[(size_t)bn*HH + lane];
  p_s[lane+64] = pooled[(size_t)bn*HH + lane + 64];
  __syncthreads();
  float ka = 0.f, qa = 0.f;
  for (int k=0;k<HH;k++) {
    float pv = p_s[k];
    ka += pv*wkey[(size_t)k*DHALF + lane];
    qa += pv*wqry[(size_t)k*DHALF + lane];
  }
  keym[(size_t)bn*DHALF + lane] = ka;
  qm[(size_t)bn*DHALF + lane] = qa;
}

// ---------------- attention row -> softmax -> topk -> adj row + rowsum ----------------
__global__ void k_attn_row(const float* __restrict__ keym, const float* __restrict__ qm,
                           const int* __restrict__ topkp, float* __restrict__ adj,
                           float* __restrict__ rowsum) {
  int bn = blockIdx.x; int b = bn / NN; int n = bn % NN;
  int tid = threadIdx.x; // 256
  __shared__ float key_s[DHALF];
  __shared__ float attv[256];
  __shared__ float red[256];
  __shared__ int redi[256];
  if (tid < DHALF) key_s[tid] = keym[(size_t)bn*DHALF + tid];
  __syncthreads();
  float sc = -1e30f;
  if (tid < NN) {
    float a = 0.f;
    const float* qrow = qm + ((size_t)b*NN + tid)*DHALF;
    for (int k=0;k<DHALF;k++) a += key_s[k]*qrow[k];
    sc = a * INV_SQRT_H;
  }
  red[tid] = sc; __syncthreads();
  for (int s=128;s>0;s>>=1){ if (tid<s) red[tid]=fmaxf(red[tid],red[tid+s]); __syncthreads(); }
  float mx = red[0]; __syncthreads();
  float e = (tid<NN) ? expf(sc-mx) : 0.f;
  red[tid] = e; __syncthreads();
  for (int s=128;s>0;s>>=1){ if (tid<s) red[tid]+=red[tid+s]; __syncthreads(); }
  float inv = 1.f/red[0]; __syncthreads();
  float av = e*inv;
  attv[tid] = (tid<NN) ? av : -1e30f;
  __syncthreads();
  int Ks = topkp[0]; if (Ks > NN) Ks = NN;
  float kth = -1e30f;
  for (int it=0; it<Ks; it++) {
    red[tid] = attv[tid]; redi[tid] = tid; __syncthreads();
    for (int s=128;s>0;s>>=1){
      if (tid<s && red[tid+s] > red[tid]) { red[tid]=red[tid+s]; redi[tid]=redi[tid+s]; }
      __syncthreads();
    }
    kth = red[0];
    if (tid==0) attv[redi[0]] = -1e30f;
    __syncthreads();
  }
  float aout = 0.f;
  if (tid < NN) {
    aout = (av >= kth) ? av : 0.f;
    if (tid == n) aout += 1.f;
    adj[((size_t)b*NN+n)*NN + tid] = aout;
  }
  red[tid] = aout; __syncthreads();
  for (int s=128;s>0;s>>=1){ if (tid<s) red[tid]+=red[tid+s]; __syncthreads(); }
  if (tid==0) rowsum[bn] = red[0];
}

// ---------------- column sums of adj ----------------
__global__ void k_colsum(const float* __restrict__ adj, float* __restrict__ cs) {
  int b = blockIdx.x;
  for (int j=threadIdx.x; j<NN; j+=blockDim.x) {
    float s = 0.f;
    for (int i=0;i<NN;i++) s += adj[((size_t)b*NN+i)*NN + j];
    cs[(size_t)b*NN + j] = s;
  }
}

// ---------------- build sparse gather lists (deterministic) ----------------
__global__ void k_sparsify(const float* __restrict__ adj, const float* __restrict__ rs,
                           const float* __restrict__ cs,
                           int* __restrict__ s2cnt, int* __restrict__ s2col, float* __restrict__ s2val,
                           int* __restrict__ s1cnt, int* __restrict__ s1col, float* __restrict__ s1val) {
  int bn = blockIdx.x; int b = bn/NN; int i = bn%NN;
  int lane = threadIdx.x; // 64
  int cnt = 0;
  for (int j0=0;j0<NN;j0+=64) {
    int j = j0+lane;
    float v = (j<NN) ? adj[((size_t)b*NN+i)*NN + j] : 0.f;
    bool nz = (v != 0.f);
    unsigned long long m = __ballot(nz);
    int pos = cnt + __popcll(m & ((1ull<<lane)-1ull));
    if (nz) { s2col[(size_t)bn*NN+pos] = j; s2val[(size_t)bn*NN+pos] = v / cs[(size_t)b*NN+j]; }
    cnt += __popcll(m);
  }
  if (lane==0) s2cnt[bn] = cnt;
  cnt = 0;
  for (int j0=0;j0<NN;j0+=64) {
    int j = j0+lane;
    float v = (j<NN) ? adj[((size_t)b*NN+j)*NN + i] : 0.f;
    bool nz = (v != 0.f);
    unsigned long long m = __ballot(nz);
    int pos = cnt + __popcll(m & ((1ull<<lane)-1ull));
    if (nz) { s1col[(size_t)bn*NN+pos] = j; s1val[(size_t)bn*NN+pos] = v / rs[(size_t)b*NN+j]; }
    cnt += __popcll(m);
  }
  if (lane==0) s1cnt[bn] = cnt;
}

// ---------------- fused gconv: concat + hop1 + hop2 (both supports), per (chunk,batch) --
// Block (c0 chunk, batch b). LDS: X0 panel [200][64] fp32 + hop panel [200][64] fp32.
// Writes 5 m-planes of X (hi/lo bf16) for its column chunk.
__global__ __launch_bounds__(512) void k_gconv_fused(
    const float* __restrict__ x, int bs, int ns, int din,
    const float* __restrict__ h, const float* __restrict__ ru,
    const int* __restrict__ cnt1, const int* __restrict__ col1, const float* __restrict__ val1,
    const int* __restrict__ cnt2, const int* __restrict__ col2, const float* __restrict__ val2,
    __hip_bfloat16* __restrict__ XH, __hip_bfloat16* __restrict__ XL,
    int d, int d_pad) {
  extern __shared__ float lds[];
  float* X0s = lds;             // [NN][CHUNK]
  float* XTs = lds + NN*CHUNK;  // hop panel, reused for S1 then S2
  int c0 = blockIdx.x*CHUNK;
  int b  = blockIdx.y;
  int tid = threadIdx.x;
  int lane = tid & 63, wid = tid >> 6;   // 8 waves

  // ---- P0: concat -> X0s + global plane m=0 ----
  for (int i = tid; i < NN*CHUNK; i += 512) {
    int n = i >> 6; int c = c0 + (i & 63);
    float v = 0.f;
    if (c < din) {
      v = x[(size_t)b*bs + (size_t)n*ns + c];
    } else if (c < d) {
      int k = c - din;
      v = h[((size_t)(b*NN+n))*HH + k];
      if (ru) v *= ru[(size_t)(b*NN+n)*256 + k];
    }
    X0s[i] = v;
    uint32_t hi, lo; splitbf(v, hi, lo);
    size_t ga = (size_t)(b*NN+n)*XROW + c;
    XH[ga] = *(__hip_bfloat16*)&hi;
    XL[ga] = *(__hip_bfloat16*)&lo;
  }
  __syncthreads();

  // ---- 4 gather phases: (S1 hop1), (S1 cheb), (S2 hop1), (S2 cheb) ----
  for (int ph = 0; ph < 4; ph++) {
    int side = ph >> 1;
    int cheb = ph & 1;
    const int* cntp = side ? cnt2 : cnt1;
    const int* colp = side ? col2 : col1;
    const float* valp = side ? val2 : val1;
    const float* src = cheb ? XTs : X0s;
    int mout = 1 + ph;
    for (int n = wid; n < NN; n += 8) {
      int bn = b*NN + n;
      int cn = cntp[bn];
      float acc = 0.f;
      for (int base = 0; base < cn; base += 64) {
        int kk = base + lane;
        int cj = 0; float vv = 0.f;
        if (kk < cn) { cj = colp[(size_t)bn*NN + kk]; vv = valp[(size_t)bn*NN + kk]; }
        int lim = min(64, cn - base);
        for (int j = 0; j < lim; j++) {
          int   cjj = __shfl(cj, j, 64);
          float vvv = __shfl(vv, j, 64);
          acc += vvv * src[cjj*CHUNK + lane];
        }
      }
      if (cheb) acc = 2.f*acc - X0s[n*CHUNK + lane];
      else      XTs[n*CHUNK + lane] = acc;
      uint32_t hi, lo; splitbf(acc, hi, lo);
      size_t ga = (size_t)mout*MSTRIDE + (size_t)bn*XROW + c0 + lane;
      XH[ga] = *(__hip_bfloat16*)&hi;
      XL[ga] = *(__hip_bfloat16*)&lo;
    }
    __syncthreads();
  }
}

// ---------------- dense via split-bf16 MFMA: Y = act( sum_m Xm @ Wm + b ) ------------
// A*W ~= Ah*Wh + Al*Wh + Ah*Wl  (3 MFMAs, fp32-grade)
// PATH 0 (gate):   RU[row*256+col] = sigmoid(v)        (OUT=256)
// PATH 1 (cand):   hnew[row*128+col] = u*h + (1-u)*tanh(v), u = RU[row*256+128+col]
template<int OUT, int PATH>
__global__ __launch_bounds__(256) void k_dense_mfma(
    const __hip_bfloat16* __restrict__ Xh, const __hip_bfloat16* __restrict__ Xl,
    const __hip_bfloat16* __restrict__ Wfh, const __hip_bfloat16* __restrict__ Wfl,
    const float* __restrict__ bias, int d_pad,
    float* __restrict__ RU, const float* __restrict__ h, float* __restrict__ hnew) {
  int tid = threadIdx.x;
  int w = tid >> 6, l = tid & 63;
  int rbase = blockIdx.x*32 + (w&1)*16;
  int cbase = blockIdx.y*128 + (w>>1)*64;
  const int NT = OUT >> 4;
  int KT = d_pad >> 5;
  f32x4 acc[4];
  #pragma unroll
  for (int q=0;q<4;q++) acc[q] = (f32x4){0.f,0.f,0.f,0.f};
  int arow = rbase + (l & 15);
  int akoff = (l >> 4) * 8;
  size_t aoff = (size_t)arow*XROW + akoff;
  size_t boff = (((size_t)(cbase>>4))*64 + l)*8;
  for (int m=0;m<5;m++) {
    for (int kt=0; kt<KT; kt++) {
      size_t ao = aoff + (size_t)m*MSTRIDE + kt*32;
      bf16x8 ah = *(const bf16x8*)(Xh + ao);
      bf16x8 al = *(const bf16x8*)(Xl + ao);
      size_t bo = boff + ((size_t)(m*KT + kt)*NT)*64*8;
      #pragma unroll
      for (int q=0;q<4;q++) {
        bf16x8 bh = *(const bf16x8*)(Wfh + bo + (size_t)q*64*8);
        bf16x8 bl = *(const bf16x8*)(Wfl + bo + (size_t)q*64*8);
        acc[q] = __builtin_amdgcn_mfma_f32_16x16x32_bf16(ah, bl, acc[q], 0, 0, 0);
        acc[q] = __builtin_amdgcn_mfma_f32_16x16x32_bf16(al, bh, acc[q], 0, 0, 0);
        acc[q] = __builtin_amdgcn_mfma_f32_16x16x32_bf16(ah, bh, acc[q], 0, 0, 0);
      }
    }
  }
  int drow0 = rbase + ((l>>4)<<2);
  int col0 = l & 15;
  #pragma unroll
  for (int q=0;q<4;q++) {
    int col = cbase + q*16 + col0;
    float bv = bias[col];
    #pragma unroll
    for (int r=0;r<4;r++) {
      int row = drow0 + r;
      float v = acc[q][r] + bv;
      if (PATH==0) {
        RU[(size_t)row*256 + col] = sigmf(v);
      } else {
        float c = tanhf(v);
        float u = RU[(size_t)row*256 + 128 + col];
        hnew[(size_t)row*HH + col] = u*h[(size_t)row*HH + col] + (1.f-u)*c;
      }
    }
  }
}

// ---------------- projection + output + next decoder input ----------------
__global__ void k_proj(const float* __restrict__ h, const float* __restrict__ pW,
                       const float* __restrict__ pb, float* __restrict__ out,
                       float* __restrict__ decx, int t) {
  int row = blockIdx.x; int lane = threadIdx.x; // 64
  const float* hr = h + (size_t)row*HH;
  float v = hr[lane]*pW[lane] + hr[lane+64]*pW[lane+64];
  for (int off=32; off; off>>=1) v += __shfl_xor(v, off, 64);
  if (lane==0) {
    float pv = v + pb[0];
    out[(size_t)t*BB*NN + row] = pv;
    decx[row] = pv;
  }
}

extern "C" void kernel_launch(void* const* d_in, const int* in_sizes, int n_in,
                              void* d_out, int out_size, void* d_ws, size_t ws_size,
                              hipStream_t stream) {
  const float* enc_in = (const float*)d_in[0];
  const float* gWih = (const float*)d_in[2];
  const float* gWhh = (const float*)d_in[3];
  const float* gbih = (const float*)d_in[4];
  const float* gbhh = (const float*)d_in[5];
  const float* attW = (const float*)d_in[6];
  const float* attb = (const float*)d_in[7];
  const float* wlc  = (const float*)d_in[8];
  const float* wkey = (const float*)d_in[9];
  const float* wqry = (const float*)d_in[10];
  const float* cWg[4] = {(const float*)d_in[11],(const float*)d_in[15],(const float*)d_in[19],(const float*)d_in[23]};
  const float* cbg[4] = {(const float*)d_in[12],(const float*)d_in[16],(const float*)d_in[20],(const float*)d_in[24]};
  const float* cWc[4] = {(const float*)d_in[13],(const float*)d_in[17],(const float*)d_in[21],(const float*)d_in[25]};
  const float* cbc[4] = {(const float*)d_in[14],(const float*)d_in[18],(const float*)d_in[22],(const float*)d_in[26]};
  const float* pW = (const float*)d_in[27];
  const float* pb = (const float*)d_in[28];
  const int* topkp = (const int*)d_in[29];
  float* out = (float*)d_out;

  // d_pad per param set (multiple of CHUNK): 0=enc l0 (d=130), 1=enc l1 (256),
  // 2=dec l0 (129), 3=dec l1 (256)
  const int d_full[4] = {130, 256, 129, 256};
  const int d_padv[4] = {192, 256, 192, 256};

  float* ws = (float*)d_ws;
  size_t off = 0;
  auto alloc = [&](size_t n) { float* p = ws + off; off += (n + 255) & ~(size_t)255; return p; };

  // ---- persistent allocations ----
  float* RS   = alloc(NB);
  float* CS   = alloc(NB);
  int*   S2CNT= (int*)alloc(NB);
  int*   S1CNT= (int*)alloc(NB);
  int*   S2COL= (int*)alloc((size_t)NB*NN);
  float* S2VAL= alloc((size_t)NB*NN);
  int*   S1COL= (int*)alloc((size_t)NB*NN);
  float* S1VAL= alloc((size_t)NB*NN);
  float* RU   = alloc((size_t)NB*256);
  float* H0A  = alloc((size_t)NB*HH);
  float* H0B  = alloc((size_t)NB*HH);
  float* H1A  = alloc((size_t)NB*HH);
  float* H1B  = alloc((size_t)NB*HH);
  float* DECX = alloc(NB);
  float* WHHT = alloc((size_t)3*HH*HH);
  __hip_bfloat16 *WGFh[4], *WGFl[4], *WCFh[4], *WCFl[4];
  for (int p=0;p<4;p++) {
    WGFh[p] = (__hip_bfloat16*)alloc((size_t)5*d_padv[p]*256/2);
    WGFl[p] = (__hip_bfloat16*)alloc((size_t)5*d_padv[p]*256/2);
    WCFh[p] = (__hip_bfloat16*)alloc((size_t)5*d_padv[p]*128/2);
    WCFl[p] = (__hip_bfloat16*)alloc((size_t)5*d_padv[p]*128/2);
  }

  // ---- union region: supports-phase scratch OR cell-phase X hi/lo planes ----
  const size_t SUP_SZ = (size_t)T_INC*NN*BB*HH   // OUTS
                      + (size_t)NB*HH            // HGRU
                      + (size_t)NB*HH            // POOL
                      + (size_t)NB*DHALF*2       // KEYM,QMM
                      + (size_t)BB*NN*NN + 4096; // ADJ + pad
  const size_t CELL_SZ = 5*MSTRIDE/2 + 5*MSTRIDE/2 + 4096;   // XH + XL (bf16)
  float* UNION = alloc(SUP_SZ > CELL_SZ ? SUP_SZ : CELL_SZ);
  // supports view
  float* OUTS = UNION;
  float* HGRU = OUTS + (size_t)T_INC*NN*BB*HH;
  float* POOL = HGRU + (size_t)NB*HH;
  float* KEYM = POOL + (size_t)NB*HH;
  float* QMM  = KEYM + (size_t)NB*DHALF;
  float* ADJ  = QMM  + (size_t)NB*DHALF;
  // cells view
  __hip_bfloat16* XH = (__hip_bfloat16*)UNION;                   // 5 hi planes
  __hip_bfloat16* XL = (__hip_bfloat16*)(UNION + 5*MSTRIDE/2);   // 5 lo planes

  if (off*sizeof(float) > ws_size) return;

  hipMemsetAsync(HGRU, 0, (size_t)NB*HH*sizeof(float), stream);
  hipMemsetAsync(H0A, 0, (size_t)NB*HH*sizeof(float), stream);
  hipMemsetAsync(H1A, 0, (size_t)NB*HH*sizeof(float), stream);
  hipMemsetAsync(DECX, 0, (size_t)NB*sizeof(float), stream);

  // ---- prep: weight transforms ----
  k_whhT<<<(3*HH*HH+255)/256, 256, 0, stream>>>(gWhh, WHHT);
  for (int p=0;p<4;p++) {
    int tg = 5*d_padv[p]*256;
    k_wshuf<<<(tg+255)/256, 256, 0, stream>>>(cWg[p], WGFh[p], WGFl[p], d_full[p], d_padv[p], 256);
    int tc = 5*d_padv[p]*128;
    k_wshuf<<<(tc+255)/256, 256, 0, stream>>>(cWc[p], WCFh[p], WCFl[p], d_full[p], d_padv[p], 128);
  }

  // ---- supports ----
  for (int t=0;t<T_INC;t++)
    k_gru_step<<<NB/4, 512, 0, stream>>>(enc_in, gWih, WHHT, gbih, gbhh, HGRU, OUTS, t);
  k_att_pool<<<NB, 64, 0, stream>>>(OUTS, attW, attb, wlc, POOL);
  k_keyquery<<<NB, 64, 0, stream>>>(POOL, wkey, wqry, KEYM, QMM);
  k_attn_row<<<NB, 256, 0, stream>>>(KEYM, QMM, topkp, ADJ, RS);
  k_colsum<<<BB, 256, 0, stream>>>(ADJ, CS);
  k_sparsify<<<NB, 64, 0, stream>>>(ADJ, RS, CS, S2CNT, S2COL, S2VAL, S1CNT, S1COL, S1VAL);

  auto gconv = [&](const float* x, int bs, int ns, int din, const float* hcur,
                   const float* ru, int pidx) {
    int d = d_full[pidx], dp = d_padv[pidx];
    dim3 gg(dp/CHUNK, BB);
    k_gconv_fused<<<gg, 512, GCONV_LDS, stream>>>(
        x, bs, ns, din, hcur, ru,
        S1CNT, S1COL, S1VAL, S2CNT, S2COL, S2VAL, XH, XL, d, dp);
  };

  auto cell = [&](const float* x, int bs, int ns, int din,
                  float** hcur, float** halt, int pidx) {
    int dp = d_padv[pidx];
    // gate
    gconv(x, bs, ns, din, *hcur, nullptr, pidx);
    k_dense_mfma<256,0><<<dim3(NB/32,2),256,0,stream>>>(XH, XL, WGFh[pidx], WGFl[pidx],
                                                        cbg[pidx], dp, RU, nullptr, nullptr);
    // candidate (+fused hnew)
    gconv(x, bs, ns, din, *hcur, RU, pidx);
    k_dense_mfma<128,1><<<dim3(NB/32,1),256,0,stream>>>(XH, XL, WCFh[pidx], WCFl[pidx],
                                                        cbc[pidx], dp, RU, *hcur, *halt);
    float* tswp = *hcur; *hcur = *halt; *halt = tswp;
  };

  float* h0cur = H0A; float* h0alt = H0B;
  float* h1cur = H1A; float* h1alt = H1B;

  for (int t=0;t<T_INC;t++) {
    cell(enc_in + (size_t)t*NN*DIN0, T_INC*NN*DIN0, DIN0, DIN0, &h0cur, &h0alt, 0);
    cell(h0cur, NN*HH, HH, HH, &h1cur, &h1alt, 1);
  }
  for (int t=0;t<T_OUTC;t++) {
    cell(DECX, NN, 1, 1, &h0cur, &h0alt, 2);
    cell(h0cur, NN*HH, HH, HH, &h1cur, &h1alt, 3);
    k_proj<<<NB,64,0,stream>>>(h1cur, pW, pb, out, DECX, t);
  }
}

// Round 7
// 14213.525 us; speedup vs baseline: 3.5018x; 2.4733x over previous
//
#include <hip/hip_runtime.h>
#include <hip/hip_bf16.h>
#include <math.h>

#define BB 32
#define T_INC 12
#define T_OUTC 12
#define NN 200
#define DIN0 2
#define HH 128
#define DHALF 64
#define NB (NN*BB)
#define XROW 256                      // fixed row stride (elems) for X planes
#define MSTRIDE ((size_t)NB*XROW)     // per-m stride in elems
#define CHUNK 64                      // column chunk per gconv block
#define KT2 7                         // k-tiles: 224 = 7*32
#define RT2 13                        // row-tiles: 208 = 13*16
#define SFRAG_PER_B ((size_t)RT2*KT2*64*8)   // 46592 elems per (mat,b)
#define PANEL_E (KT2*4*64*8)          // 14336 bf16 per LDS panel
#define GCONV_LDS (4*PANEL_E*2)       // 114,688 B
#define INV_SQRT_H 0.08838834764831845f

typedef __attribute__((ext_vector_type(8))) short bf16x8;
typedef __attribute__((ext_vector_type(4))) float f32x4;

__device__ __forceinline__ float sigmf(float x){ return 1.f/(1.f+expf(-x)); }
__device__ __forceinline__ float bfu(uint32_t b){ union{uint32_t u;float f;}v; v.u=b<<16; return v.f; }
__device__ __forceinline__ uint32_t fbf(float f){ union{float f2;uint32_t u;}v; v.f2=f; return (v.u + 0x7fffu + ((v.u>>16)&1u))>>16; }
// split v into bf16 hi + bf16 lo (v ~= hi + lo to ~17 mantissa bits)
__device__ __forceinline__ void splitbf(float v, uint32_t& hi, uint32_t& lo){
  hi = fbf(v);
  lo = fbf(v - bfu(hi));
}

// ---------------- prep: transpose Whh (3H x H) -> (H x 3H) ----------------
__global__ void k_whhT(const float* __restrict__ Whh, float* __restrict__ WT) {
  int idx = blockIdx.x*256 + threadIdx.x;
  if (idx >= 3*HH*HH) return;
  int i3 = idx / HH; int k = idx % HH;
  WT[(size_t)k*(3*HH) + i3] = Whh[idx];
}

// ---------------- prep: shuffle dense weights into MFMA B-fragment layout, hi/lo ----
__global__ void k_wshuf(const float* __restrict__ W, __hip_bfloat16* __restrict__ Wfh,
                        __hip_bfloat16* __restrict__ Wfl, int d, int d_pad, int OUT) {
  int idx = blockIdx.x*256 + threadIdx.x;
  int total = 5*d_pad*OUT;
  if (idx >= total) return;
  int o = idx % OUT; int tmp = idx / OUT; int k = tmp % d_pad; int m = tmp / d_pad;
  float v = (k < d) ? W[((size_t)k*5 + m)*OUT + o] : 0.f;
  int kt = k >> 5, kr = k & 31;
  int lane = ((kr>>3)<<4) | (o & 15);
  int j = kr & 7;
  int nt = o >> 4;
  int KT = d_pad >> 5, NT = OUT >> 4;
  size_t addr = ((((size_t)m*KT + kt)*NT + nt)*64 + (size_t)lane)*8 + j;
  uint32_t hi, lo; splitbf(v, hi, lo);
  Wfh[addr] = *(__hip_bfloat16*)&hi;
  Wfl[addr] = *(__hip_bfloat16*)&lo;
}

// ---------------- prep: shuffle S1/S2 (dense, from adj) into A-frag layout, hi/lo ----
// s1[n][j] = adj[j][n]/rs[j] ; s2[n][j] = adj[n][j]/cs[j] ; padded to 208x224
__global__ void k_sshuf(const float* __restrict__ adj, const float* __restrict__ rs,
                        const float* __restrict__ cs,
                        __hip_bfloat16* __restrict__ SFH, __hip_bfloat16* __restrict__ SFL) {
  const int PER_B = 208*224;
  int idx = blockIdx.x*256 + threadIdx.x;
  if (idx >= 2*BB*PER_B) return;
  int e = idx % PER_B; int t2 = idx / PER_B; int b = t2 % BB; int mat = t2 / BB;
  int n = e / 224; int j = e % 224;
  float v = 0.f;
  if (n < NN && j < NN) {
    if (mat == 0) v = adj[((size_t)b*NN + j)*NN + n] / rs[(size_t)b*NN + j];
    else          v = adj[((size_t)b*NN + n)*NN + j] / cs[(size_t)b*NN + j];
  }
  int rt = n >> 4, rr = n & 15, kt = j >> 5, kr = j & 31;
  int lane = ((kr >> 3) << 4) | rr;
  int jj = kr & 7;
  size_t addr = ((size_t)(mat*BB + b)*RT2*KT2 + (size_t)(rt*KT2 + kt))*512
              + (size_t)lane*8 + jj;
  uint32_t hi, lo; splitbf(v, hi, lo);
  SFH[addr] = *(__hip_bfloat16*)&hi;
  SFL[addr] = *(__hip_bfloat16*)&lo;
}

// ---------------- GRU step (WhhT coalesced) ----------------
__global__ __launch_bounds__(512) void k_gru_step(
    const float* __restrict__ enc_in, const float* __restrict__ Wih,
    const float* __restrict__ WhhT, const float* __restrict__ bih,
    const float* __restrict__ bhh, float* __restrict__ h,
    float* __restrict__ outs, int t) {
  int row0 = blockIdx.x * 4;
  int tid = threadIdx.x;
  int rr = tid >> 7;
  int i = tid & 127;
  int row = row0 + rr;
  int n = row / BB, b = row % BB;
  __shared__ float hs[4][HH];
  hs[rr][i] = h[(size_t)row*HH + i];
  __syncthreads();
  float x0 = enc_in[(((size_t)b*T_INC + t)*NN + n)*DIN0 + 0];
  float x1 = enc_in[(((size_t)b*T_INC + t)*NN + n)*DIN0 + 1];
  float ir = Wih[(0*HH+i)*2+0]*x0 + Wih[(0*HH+i)*2+1]*x1 + bih[0*HH+i];
  float iz = Wih[(1*HH+i)*2+0]*x0 + Wih[(1*HH+i)*2+1]*x1 + bih[1*HH+i];
  float ig = Wih[(2*HH+i)*2+0]*x0 + Wih[(2*HH+i)*2+1]*x1 + bih[2*HH+i];
  float hr = bhh[i], hz = bhh[HH+i], hg = bhh[2*HH+i];
  for (int k=0;k<HH;k++) {
    float hv = hs[rr][k];
    const float* wr = WhhT + (size_t)k*(3*HH);
    hr += wr[i]*hv; hz += wr[i+128]*hv; hg += wr[i+256]*hv;
  }
  float r = sigmf(ir+hr);
  float z = sigmf(iz+hz);
  float nn2 = tanhf(ig + r*hg);
  float hn = (1.f-z)*nn2 + z*hs[rr][i];
  h[(size_t)row*HH+i] = hn;
  outs[(((size_t)t*NN+n)*BB+b)*HH + i] = hn;
}

// ---------------- length-attention pooling ----------------
__global__ void k_att_pool(const float* __restrict__ outs, const float* __restrict__ attW,
                           const float* __restrict__ attb, const float* __restrict__ wlc,
                           float* __restrict__ pooled) {
  int row = blockIdx.x; int n = row / BB, b = row % BB;
  int lane = threadIdx.x; // 64
  __shared__ float o_s[T_INC][HH];
  for (int t=0;t<T_INC;t++)
    for (int k=lane;k<HH;k+=64)
      o_s[t][k] = outs[(((size_t)t*NN+n)*BB+b)*HH + k];
  __syncthreads();
  float wc = wlc[lane];
  float ab = attb[lane];
  float logit[T_INC];
  for (int t=0;t<T_INC;t++) {
    float acc = ab;
    const float* wr = attW + (size_t)lane*HH;
    for (int k=0;k<HH;k++) acc += wr[k]*o_s[t][k];
    logit[t] = fmaxf(acc, 0.f)*wc;
  }
  for (int off=32; off; off>>=1)
    for (int t=0;t<T_INC;t++) logit[t] += __shfl_xor(logit[t], off, 64);
  float mx = -1e30f;
  for (int t=0;t<T_INC;t++) mx = fmaxf(mx, logit[t]);
  float s = 0.f;
  for (int t=0;t<T_INC;t++) { logit[t] = expf(logit[t]-mx); s += logit[t]; }
  float inv = 1.f/s;
  for (int k=lane;k<HH;k+=64) {
    float acc = 0.f;
    for (int t=0;t<T_INC;t++) acc += o_s[t][k]*logit[t];
    pooled[((size_t)b*NN+n)*HH + k] = acc*inv;
  }
}

// ---------------- key/query projections ----------------
__global__ void k_keyquery(const float* __restrict__ pooled, const float* __restrict__ wkey,
                           const float* __restrict__ wqry, float* __restrict__ keym,
                           float* __restrict__ qm) {
  int bn = blockIdx.x; int lane = threadIdx.x; // 64
  __shared__ float p_s[HH];
  p_s[lane] = pooled[(size_t)bn*HH + lane];
  p_s[lane+64] = pooled[(size_t)bn*HH + lane + 64];
  __syncthreads();
  float ka = 0.f, qa = 0.f;
  for (int k=0;k<HH;k++) {
    float pv = p_s[k];
    ka += pv*wkey[(size_t)k*DHALF + lane];
    qa += pv*wqry[(size_t)k*DHALF + lane];
  }
  keym[(size_t)bn*DHALF + lane] = ka;
  qm[(size_t)bn*DHALF + lane] = qa;
}

// ---------------- attention row -> softmax -> topk -> adj row + rowsum ----------------
__global__ void k_attn_row(const float* __restrict__ keym, const float* __restrict__ qm,
                           const int* __restrict__ topkp, float* __restrict__ adj,
                           float* __restrict__ rowsum) {
  int bn = blockIdx.x; int b = bn / NN; int n = bn % NN;
  int tid = threadIdx.x; // 256
  __shared__ float key_s[DHALF];
  __shared__ float attv[256];
  __shared__ float red[256];
  __shared__ int redi[256];
  if (tid < DHALF) key_s[tid] = keym[(size_t)bn*DHALF + tid];
  __syncthreads();
  float sc = -1e30f;
  if (tid < NN) {
    float a = 0.f;
    const float* qrow = qm + ((size_t)b*NN + tid)*DHALF;
    for (int k=0;k<DHALF;k++) a += key_s[k]*qrow[k];
    sc = a * INV_SQRT_H;
  }
  red[tid] = sc; __syncthreads();
  for (int s=128;s>0;s>>=1){ if (tid<s) red[tid]=fmaxf(red[tid],red[tid+s]); __syncthreads(); }
  float mx = red[0]; __syncthreads();
  float e = (tid<NN) ? expf(sc-mx) : 0.f;
  red[tid] = e; __syncthreads();
  for (int s=128;s>0;s>>=1){ if (tid<s) red[tid]+=red[tid+s]; __syncthreads(); }
  float inv = 1.f/red[0]; __syncthreads();
  float av = e*inv;
  attv[tid] = (tid<NN) ? av : -1e30f;
  __syncthreads();
  int Ks = topkp[0]; if (Ks > NN) Ks = NN;
  float kth = -1e30f;
  for (int it=0; it<Ks; it++) {
    red[tid] = attv[tid]; redi[tid] = tid; __syncthreads();
    for (int s=128;s>0;s>>=1){
      if (tid<s && red[tid+s] > red[tid]) { red[tid]=red[tid+s]; redi[tid]=redi[tid+s]; }
      __syncthreads();
    }
    kth = red[0];
    if (tid==0) attv[redi[0]] = -1e30f;
    __syncthreads();
  }
  float aout = 0.f;
  if (tid < NN) {
    aout = (av >= kth) ? av : 0.f;
    if (tid == n) aout += 1.f;
    adj[((size_t)b*NN+n)*NN + tid] = aout;
  }
  red[tid] = aout; __syncthreads();
  for (int s=128;s>0;s>>=1){ if (tid<s) red[tid]+=red[tid+s]; __syncthreads(); }
  if (tid==0) rowsum[bn] = red[0];
}

// ---------------- column sums of adj ----------------
__global__ void k_colsum(const float* __restrict__ adj, float* __restrict__ cs) {
  int b = blockIdx.x;
  for (int j=threadIdx.x; j<NN; j+=blockDim.x) {
    float s = 0.f;
    for (int i=0;i<NN;i++) s += adj[((size_t)b*NN+i)*NN + j];
    cs[(size_t)b*NN + j] = s;
  }
}

// ---------------- fused gconv via MFMA: concat + 4 hops per (chunk,batch) ------------
// LDS: X0 panel + XT panel, each in B-frag layout, hi/lo bf16 (4 x 28,672 B).
// A-operand = pre-shuffled S fragments (global, L2-resident).
__global__ __launch_bounds__(256) void k_gconv_mfma(
    const float* __restrict__ x, int bs, int ns, int din,
    const float* __restrict__ h, const float* __restrict__ ru,
    const __hip_bfloat16* __restrict__ SFH, const __hip_bfloat16* __restrict__ SFL,
    __hip_bfloat16* __restrict__ XH, __hip_bfloat16* __restrict__ XL, int d) {
  extern __shared__ char ldsc[];
  ushort* X0H = (ushort*)ldsc;          // [KT2*4][64][8]
  ushort* X0L = X0H + PANEL_E;
  ushort* XTH = X0L + PANEL_E;
  ushort* XTL = XTH + PANEL_E;
  int c0 = blockIdx.x*CHUNK;
  int b  = blockIdx.y;
  int tid = threadIdx.x;
  int l = tid & 63, wid = tid >> 6;     // 4 waves

  // zero all panels (covers pad rows 200..223 and XT rows never written)
  { uint4 z = make_uint4(0,0,0,0);
    uint4* p = (uint4*)ldsc;
    for (int i = tid; i < GCONV_LDS/16; i += 256) p[i] = z; }
  __syncthreads();

  // concat -> X0 frag panel + global plane m=0
  for (int i = tid; i < NN*CHUNK; i += 256) {
    int n = i >> 6, cc = i & 63;
    int c = c0 + cc;
    float v = 0.f;
    if (c < din) {
      v = x[(size_t)b*bs + (size_t)n*ns + c];
    } else if (c < d) {
      int k = c - din;
      v = h[((size_t)(b*NN+n))*HH + k];
      if (ru) v *= ru[(size_t)(b*NN+n)*256 + k];
    }
    uint32_t hi, lo; splitbf(v, hi, lo);
    int kt = n >> 5, kr = n & 31;
    int ln = ((kr>>3)<<4) | (cc & 15), jj = kr & 7, q = cc >> 4;
    int fa = ((kt*4 + q)*64 + ln)*8 + jj;
    X0H[fa] = (ushort)hi; X0L[fa] = (ushort)lo;
    size_t ga = (size_t)(b*NN+n)*XROW + c;
    XH[ga] = *(__hip_bfloat16*)&hi;
    XL[ga] = *(__hip_bfloat16*)&lo;
  }
  __syncthreads();

  // 4 phases: (S1 hop1)->XT,m1 ; (S1 cheb XT)->m2 ; (S2 hop1)->XT,m3 ; (S2 cheb XT)->m4
  for (int ph = 0; ph < 4; ph++) {
    int side = ph >> 1, cheb = ph & 1;
    const ushort* BH = cheb ? XTH : X0H;
    const ushort* BL = cheb ? XTL : X0L;
    const __hip_bfloat16* AH = SFH + (size_t)(side*BB + b)*SFRAG_PER_B;
    const __hip_bfloat16* AL = SFL + (size_t)(side*BB + b)*SFRAG_PER_B;
    int mout = 1 + ph;
    for (int rt = wid; rt < RT2; rt += 4) {
      f32x4 acc[4];
      #pragma unroll
      for (int q=0;q<4;q++) acc[q] = (f32x4){0.f,0.f,0.f,0.f};
      for (int kt = 0; kt < KT2; kt++) {
        size_t aoff = ((size_t)(rt*KT2+kt)*64 + l)*8;
        bf16x8 ah = *(const bf16x8*)(AH + aoff);
        bf16x8 al = *(const bf16x8*)(AL + aoff);
        #pragma unroll
        for (int q=0;q<4;q++) {
          int boff = ((kt*4+q)*64 + l)*8;
          bf16x8 bh = *(const bf16x8*)(BH + boff);
          bf16x8 bl = *(const bf16x8*)(BL + boff);
          acc[q] = __builtin_amdgcn_mfma_f32_16x16x32_bf16(ah, bl, acc[q], 0, 0, 0);
          acc[q] = __builtin_amdgcn_mfma_f32_16x16x32_bf16(al, bh, acc[q], 0, 0, 0);
          acc[q] = __builtin_amdgcn_mfma_f32_16x16x32_bf16(ah, bh, acc[q], 0, 0, 0);
        }
      }
      int colb = l & 15;
      #pragma unroll
      for (int q=0;q<4;q++) {
        int cc = q*16 + colb;
        #pragma unroll
        for (int r=0;r<4;r++) {
          int n = rt*16 + ((l>>4)<<2) + r;
          float v = acc[q][r];
          int kt2 = n >> 5, kr = n & 31;
          int ln = ((kr>>3)<<4) | colb, jj = kr & 7;
          int fa = ((kt2*4 + q)*64 + ln)*8 + jj;
          if (cheb) {
            uint32_t h2 = X0H[fa], l2 = X0L[fa];
            v = 2.f*v - (bfu(h2) + bfu(l2));
          }
          uint32_t hi, lo; splitbf(v, hi, lo);
          if (!cheb) { XTH[fa] = (ushort)hi; XTL[fa] = (ushort)lo; }
          if (n < NN) {
            size_t ga = (size_t)mout*MSTRIDE + (size_t)(b*NN+n)*XROW + c0 + cc;
            XH[ga] = *(__hip_bfloat16*)&hi;
            XL[ga] = *(__hip_bfloat16*)&lo;
          }
        }
      }
    }
    __syncthreads();
  }
}

// ---------------- dense via split-bf16 MFMA: Y = act( sum_m Xm @ Wm + b ) ------------
// PATH 0 (gate):   RU[row*256+col] = sigmoid(v)        (OUT=256)
// PATH 1 (cand):   hnew[row*128+col] = u*h + (1-u)*tanh(v), u = RU[row*256+128+col]
template<int OUT, int PATH>
__global__ __launch_bounds__(256) void k_dense_mfma(
    const __hip_bfloat16* __restrict__ Xh, const __hip_bfloat16* __restrict__ Xl,
    const __hip_bfloat16* __restrict__ Wfh, const __hip_bfloat16* __restrict__ Wfl,
    const float* __restrict__ bias, int d_pad,
    float* __restrict__ RU, const float* __restrict__ h, float* __restrict__ hnew) {
  int tid = threadIdx.x;
  int w = tid >> 6, l = tid & 63;
  int rbase = blockIdx.x*32 + (w&1)*16;
  int cbase = blockIdx.y*128 + (w>>1)*64;
  const int NT = OUT >> 4;
  int KT = d_pad >> 5;
  f32x4 acc[4];
  #pragma unroll
  for (int q=0;q<4;q++) acc[q] = (f32x4){0.f,0.f,0.f,0.f};
  int arow = rbase + (l & 15);
  int akoff = (l >> 4) * 8;
  size_t aoff = (size_t)arow*XROW + akoff;
  size_t boff = (((size_t)(cbase>>4))*64 + l)*8;
  for (int m=0;m<5;m++) {
    for (int kt=0; kt<KT; kt++) {
      size_t ao = aoff + (size_t)m*MSTRIDE + kt*32;
      bf16x8 ah = *(const bf16x8*)(Xh + ao);
      bf16x8 al = *(const bf16x8*)(Xl + ao);
      size_t bo = boff + ((size_t)(m*KT + kt)*NT)*512;
      #pragma unroll
      for (int q=0;q<4;q++) {
        bf16x8 bh = *(const bf16x8*)(Wfh + bo + (size_t)q*512);
        bf16x8 bl = *(const bf16x8*)(Wfl + bo + (size_t)q*512);
        acc[q] = __builtin_amdgcn_mfma_f32_16x16x32_bf16(ah, bl, acc[q], 0, 0, 0);
        acc[q] = __builtin_amdgcn_mfma_f32_16x16x32_bf16(al, bh, acc[q], 0, 0, 0);
        acc[q] = __builtin_amdgcn_mfma_f32_16x16x32_bf16(ah, bh, acc[q], 0, 0, 0);
      }
    }
  }
  int drow0 = rbase + ((l>>4)<<2);
  int col0 = l & 15;
  #pragma unroll
  for (int q=0;q<4;q++) {
    int col = cbase + q*16 + col0;
    float bv = bias[col];
    #pragma unroll
    for (int r=0;r<4;r++) {
      int row = drow0 + r;
      float v = acc[q][r] + bv;
      if (PATH==0) {
        RU[(size_t)row*256 + col] = sigmf(v);
      } else {
        float c = tanhf(v);
        float u = RU[(size_t)row*256 + 128 + col];
        hnew[(size_t)row*HH + col] = u*h[(size_t)row*HH + col] + (1.f-u)*c;
      }
    }
  }
}

// ---------------- projection + output + next decoder input ----------------
__global__ void k_proj(const float* __restrict__ h, const float* __restrict__ pW,
                       const float* __restrict__ pb, float* __restrict__ out,
                       float* __restrict__ decx, int t) {
  int row = blockIdx.x; int lane = threadIdx.x; // 64
  const float* hr = h + (size_t)row*HH;
  float v = hr[lane]*pW[lane] + hr[lane+64]*pW[lane+64];
  for (int off=32; off; off>>=1) v += __shfl_xor(v, off, 64);
  if (lane==0) {
    float pv = v + pb[0];
    out[(size_t)t*BB*NN + row] = pv;
    decx[row] = pv;
  }
}

extern "C" void kernel_launch(void* const* d_in, const int* in_sizes, int n_in,
                              void* d_out, int out_size, void* d_ws, size_t ws_size,
                              hipStream_t stream) {
  const float* enc_in = (const float*)d_in[0];
  const float* gWih = (const float*)d_in[2];
  const float* gWhh = (const float*)d_in[3];
  const float* gbih = (const float*)d_in[4];
  const float* gbhh = (const float*)d_in[5];
  const float* attW = (const float*)d_in[6];
  const float* attb = (const float*)d_in[7];
  const float* wlc  = (const float*)d_in[8];
  const float* wkey = (const float*)d_in[9];
  const float* wqry = (const float*)d_in[10];
  const float* cWg[4] = {(const float*)d_in[11],(const float*)d_in[15],(const float*)d_in[19],(const float*)d_in[23]};
  const float* cbg[4] = {(const float*)d_in[12],(const float*)d_in[16],(const float*)d_in[20],(const float*)d_in[24]};
  const float* cWc[4] = {(const float*)d_in[13],(const float*)d_in[17],(const float*)d_in[21],(const float*)d_in[25]};
  const float* cbc[4] = {(const float*)d_in[14],(const float*)d_in[18],(const float*)d_in[22],(const float*)d_in[26]};
  const float* pW = (const float*)d_in[27];
  const float* pb = (const float*)d_in[28];
  const int* topkp = (const int*)d_in[29];
  float* out = (float*)d_out;

  // d_pad per param set (multiple of CHUNK): 0=enc l0 (d=130), 1=enc l1 (256),
  // 2=dec l0 (129), 3=dec l1 (256)
  const int d_full[4] = {130, 256, 129, 256};
  const int d_padv[4] = {192, 256, 192, 256};

  float* ws = (float*)d_ws;
  size_t off = 0;
  auto alloc = [&](size_t n) { float* p = ws + off; off += (n + 255) & ~(size_t)255; return p; };

  // ---- persistent allocations ----
  float* RS   = alloc(NB);
  float* CS   = alloc(NB);
  float* RU   = alloc((size_t)NB*256);
  float* H0A  = alloc((size_t)NB*HH);
  float* H0B  = alloc((size_t)NB*HH);
  float* H1A  = alloc((size_t)NB*HH);
  float* H1B  = alloc((size_t)NB*HH);
  float* DECX = alloc(NB);
  float* WHHT = alloc((size_t)3*HH*HH);
  __hip_bfloat16* SFH = (__hip_bfloat16*)alloc((size_t)2*BB*SFRAG_PER_B/2);
  __hip_bfloat16* SFL = (__hip_bfloat16*)alloc((size_t)2*BB*SFRAG_PER_B/2);
  __hip_bfloat16 *WGFh[4], *WGFl[4], *WCFh[4], *WCFl[4];
  for (int p=0;p<4;p++) {
    WGFh[p] = (__hip_bfloat16*)alloc((size_t)5*d_padv[p]*256/2);
    WGFl[p] = (__hip_bfloat16*)alloc((size_t)5*d_padv[p]*256/2);
    WCFh[p] = (__hip_bfloat16*)alloc((size_t)5*d_padv[p]*128/2);
    WCFl[p] = (__hip_bfloat16*)alloc((size_t)5*d_padv[p]*128/2);
  }

  // ---- union region: supports-phase scratch OR cell-phase X hi/lo planes ----
  const size_t SUP_SZ = (size_t)T_INC*NN*BB*HH   // OUTS
                      + (size_t)NB*HH            // HGRU
                      + (size_t)NB*HH            // POOL
                      + (size_t)NB*DHALF*2       // KEYM,QMM
                      + (size_t)BB*NN*NN + 4096; // ADJ + pad
  const size_t CELL_SZ = 5*MSTRIDE/2 + 5*MSTRIDE/2 + 4096;   // XH + XL (bf16)
  float* UNION = alloc(SUP_SZ > CELL_SZ ? SUP_SZ : CELL_SZ);
  // supports view
  float* OUTS = UNION;
  float* HGRU = OUTS + (size_t)T_INC*NN*BB*HH;
  float* POOL = HGRU + (size_t)NB*HH;
  float* KEYM = POOL + (size_t)NB*HH;
  float* QMM  = KEYM + (size_t)NB*DHALF;
  float* ADJ  = QMM  + (size_t)NB*DHALF;
  // cells view
  __hip_bfloat16* XH = (__hip_bfloat16*)UNION;                   // 5 hi planes
  __hip_bfloat16* XL = (__hip_bfloat16*)(UNION + 5*MSTRIDE/2);   // 5 lo planes

  if (off*sizeof(float) > ws_size) return;

  hipMemsetAsync(HGRU, 0, (size_t)NB*HH*sizeof(float), stream);
  hipMemsetAsync(H0A, 0, (size_t)NB*HH*sizeof(float), stream);
  hipMemsetAsync(H1A, 0, (size_t)NB*HH*sizeof(float), stream);
  hipMemsetAsync(DECX, 0, (size_t)NB*sizeof(float), stream);

  // ---- prep: weight transforms ----
  k_whhT<<<(3*HH*HH+255)/256, 256, 0, stream>>>(gWhh, WHHT);
  for (int p=0;p<4;p++) {
    int tg = 5*d_padv[p]*256;
    k_wshuf<<<(tg+255)/256, 256, 0, stream>>>(cWg[p], WGFh[p], WGFl[p], d_full[p], d_padv[p], 256);
    int tc = 5*d_padv[p]*128;
    k_wshuf<<<(tc+255)/256, 256, 0, stream>>>(cWc[p], WCFh[p], WCFl[p], d_full[p], d_padv[p], 128);
  }

  // ---- supports ----
  for (int t=0;t<T_INC;t++)
    k_gru_step<<<NB/4, 512, 0, stream>>>(enc_in, gWih, WHHT, gbih, gbhh, HGRU, OUTS, t);
  k_att_pool<<<NB, 64, 0, stream>>>(OUTS, attW, attb, wlc, POOL);
  k_keyquery<<<NB, 64, 0, stream>>>(POOL, wkey, wqry, KEYM, QMM);
  k_attn_row<<<NB, 256, 0, stream>>>(KEYM, QMM, topkp, ADJ, RS);
  k_colsum<<<BB, 256, 0, stream>>>(ADJ, CS);
  { int tot = 2*BB*208*224;
    k_sshuf<<<(tot+255)/256, 256, 0, stream>>>(ADJ, RS, CS, SFH, SFL); }

  auto gconv = [&](const float* x, int bs, int ns, int din, const float* hcur,
                   const float* ru, int pidx) {
    int d = d_full[pidx], dp = d_padv[pidx];
    dim3 gg(dp/CHUNK, BB);
    k_gconv_mfma<<<gg, 256, GCONV_LDS, stream>>>(
        x, bs, ns, din, hcur, ru, SFH, SFL, XH, XL, d);
  };

  auto cell = [&](const float* x, int bs, int ns, int din,
                  float** hcur, float** halt, int pidx) {
    int dp = d_padv[pidx];
    // gate
    gconv(x, bs, ns, din, *hcur, nullptr, pidx);
    k_dense_mfma<256,0><<<dim3(NB/32,2),256,0,stream>>>(XH, XL, WGFh[pidx], WGFl[pidx],
                                                        cbg[pidx], dp, RU, nullptr, nullptr);
    // candidate (+fused hnew)
    gconv(x, bs, ns, din, *hcur, RU, pidx);
    k_dense_mfma<128,1><<<dim3(NB/32,1),256,0,stream>>>(XH, XL, WCFh[pidx], WCFl[pidx],
                                                        cbc[pidx], dp, RU, *hcur, *halt);
    float* tswp = *hcur; *hcur = *halt; *halt = tswp;
  };

  float* h0cur = H0A; float* h0alt = H0B;
  float* h1cur = H1A; float* h1alt = H1B;

  for (int t=0;t<T_INC;t++) {
    cell(enc_in + (size_t)t*NN*DIN0, T_INC*NN*DIN0, DIN0, DIN0, &h0cur, &h0alt, 0);
    cell(h0cur, NN*HH, HH, HH, &h1cur, &h1alt, 1);
  }
  for (int t=0;t<T_OUTC;t++) {
    cell(DECX, NN, 1, 1, &h0cur, &h0alt, 2);
    cell(h0cur, NN*HH, HH, HH, &h1cur, &h1alt, 3);
    k_proj<<<NB,64,0,stream>>>(h1cur, pW, pb, out, DECX, t);
  }
}

// Round 8
// 11628.307 us; speedup vs baseline: 4.2803x; 1.2223x over previous
//
#include <hip/hip_runtime.h>
#include <hip/hip_bf16.h>
#include <math.h>

#define BB 32
#define T_INC 12
#define T_OUTC 12
#define NN 200
#define DIN0 2
#define HH 128
#define DHALF 64
#define NB (NN*BB)
#define XROW 256                      // fixed row stride (elems) for X planes
#define MSTRIDE ((size_t)NB*XROW)     // per-m stride in elems (u32 each: hi|lo<<16)
#define CHUNK 32                      // column chunk per gconv block
#define QT 2                          // 16-col q-tiles per chunk
#define KT2 7                         // S k-tiles: 224 = 7*32
#define RT2 13                        // S row-tiles: 208 = 13*16
#define SFRAG_PER_B ((size_t)RT2*KT2*64*8)   // elems per (mat,b)
#define PANEL_E (KT2*QT*64*8)         // 7168 bf16 per LDS panel
#define GCONV_LDS (4*PANEL_E*2)       // 57,344 B
#define INV_SQRT_H 0.08838834764831845f

typedef __attribute__((ext_vector_type(8))) short bf16x8;
typedef __attribute__((ext_vector_type(4))) float f32x4;

__device__ __forceinline__ float sigmf(float x){ return 1.f/(1.f+expf(-x)); }
__device__ __forceinline__ float bfu(uint32_t b){ union{uint32_t u;float f;}v; v.u=b<<16; return v.f; }
__device__ __forceinline__ uint32_t fbf(float f){ union{float f2;uint32_t u;}v; v.f2=f; return (v.u + 0x7fffu + ((v.u>>16)&1u))>>16; }
// split v into bf16 hi + bf16 lo (v ~= hi + lo to ~17 mantissa bits)
__device__ __forceinline__ void splitbf(float v, uint32_t& hi, uint32_t& lo){
  hi = fbf(v);
  lo = fbf(v - bfu(hi));
}
__device__ __forceinline__ uint32_t packsplit(float v){
  uint32_t hi, lo; splitbf(v, hi, lo);
  return hi | (lo << 16);
}

// ---------------- prep: transpose Whh (3H x H) -> (H x 3H) ----------------
__global__ void k_whhT(const float* __restrict__ Whh, float* __restrict__ WT) {
  int idx = blockIdx.x*256 + threadIdx.x;
  if (idx >= 3*HH*HH) return;
  int i3 = idx / HH; int k = idx % HH;
  WT[(size_t)k*(3*HH) + i3] = Whh[idx];
}

// ---------------- prep: shuffle dense weights into MFMA B-fragment layout, hi/lo ----
__global__ void k_wshuf(const float* __restrict__ W, __hip_bfloat16* __restrict__ Wfh,
                        __hip_bfloat16* __restrict__ Wfl, int d, int d_pad, int OUT) {
  int idx = blockIdx.x*256 + threadIdx.x;
  int total = 5*d_pad*OUT;
  if (idx >= total) return;
  int o = idx % OUT; int tmp = idx / OUT; int k = tmp % d_pad; int m = tmp / d_pad;
  float v = (k < d) ? W[((size_t)k*5 + m)*OUT + o] : 0.f;
  int kt = k >> 5, kr = k & 31;
  int lane = ((kr>>3)<<4) | (o & 15);
  int j = kr & 7;
  int nt = o >> 4;
  int KT = d_pad >> 5, NT = OUT >> 4;
  size_t addr = ((((size_t)m*KT + kt)*NT + nt)*64 + (size_t)lane)*8 + j;
  uint32_t hi, lo; splitbf(v, hi, lo);
  Wfh[addr] = *(__hip_bfloat16*)&hi;
  Wfl[addr] = *(__hip_bfloat16*)&lo;
}

// ---------------- prep: shuffle S1/S2 (dense, from adj) into A-frag layout, hi/lo ----
// s1[n][j] = adj[j][n]/rs[j] ; s2[n][j] = adj[n][j]/cs[j] ; padded to 208x224
__global__ void k_sshuf(const float* __restrict__ adj, const float* __restrict__ rs,
                        const float* __restrict__ cs,
                        __hip_bfloat16* __restrict__ SFH, __hip_bfloat16* __restrict__ SFL) {
  const int PER_B = 208*224;
  int idx = blockIdx.x*256 + threadIdx.x;
  if (idx >= 2*BB*PER_B) return;
  int e = idx % PER_B; int t2 = idx / PER_B; int b = t2 % BB; int mat = t2 / BB;
  int n = e / 224; int j = e % 224;
  float v = 0.f;
  if (n < NN && j < NN) {
    if (mat == 0) v = adj[((size_t)b*NN + j)*NN + n] / rs[(size_t)b*NN + j];
    else          v = adj[((size_t)b*NN + n)*NN + j] / cs[(size_t)b*NN + j];
  }
  int rt = n >> 4, rr = n & 15, kt = j >> 5, kr = j & 31;
  int lane = ((kr >> 3) << 4) | rr;
  int jj = kr & 7;
  size_t addr = ((size_t)(mat*BB + b)*RT2*KT2 + (size_t)(rt*KT2 + kt))*512
              + (size_t)lane*8 + jj;
  uint32_t hi, lo; splitbf(v, hi, lo);
  SFH[addr] = *(__hip_bfloat16*)&hi;
  SFL[addr] = *(__hip_bfloat16*)&lo;
}

// ---------------- GRU step (WhhT coalesced) ----------------
__global__ __launch_bounds__(512) void k_gru_step(
    const float* __restrict__ enc_in, const float* __restrict__ Wih,
    const float* __restrict__ WhhT, const float* __restrict__ bih,
    const float* __restrict__ bhh, float* __restrict__ h,
    float* __restrict__ outs, int t) {
  int row0 = blockIdx.x * 4;
  int tid = threadIdx.x;
  int rr = tid >> 7;
  int i = tid & 127;
  int row = row0 + rr;
  int n = row / BB, b = row % BB;
  __shared__ float hs[4][HH];
  hs[rr][i] = h[(size_t)row*HH + i];
  __syncthreads();
  float x0 = enc_in[(((size_t)b*T_INC + t)*NN + n)*DIN0 + 0];
  float x1 = enc_in[(((size_t)b*T_INC + t)*NN + n)*DIN0 + 1];
  float ir = Wih[(0*HH+i)*2+0]*x0 + Wih[(0*HH+i)*2+1]*x1 + bih[0*HH+i];
  float iz = Wih[(1*HH+i)*2+0]*x0 + Wih[(1*HH+i)*2+1]*x1 + bih[1*HH+i];
  float ig = Wih[(2*HH+i)*2+0]*x0 + Wih[(2*HH+i)*2+1]*x1 + bih[2*HH+i];
  float hr = bhh[i], hz = bhh[HH+i], hg = bhh[2*HH+i];
  for (int k=0;k<HH;k++) {
    float hv = hs[rr][k];
    const float* wr = WhhT + (size_t)k*(3*HH);
    hr += wr[i]*hv; hz += wr[i+128]*hv; hg += wr[i+256]*hv;
  }
  float r = sigmf(ir+hr);
  float z = sigmf(iz+hz);
  float nn2 = tanhf(ig + r*hg);
  float hn = (1.f-z)*nn2 + z*hs[rr][i];
  h[(size_t)row*HH+i] = hn;
  outs[(((size_t)t*NN+n)*BB+b)*HH + i] = hn;
}

// ---------------- length-attention pooling ----------------
__global__ void k_att_pool(const float* __restrict__ outs, const float* __restrict__ attW,
                           const float* __restrict__ attb, const float* __restrict__ wlc,
                           float* __restrict__ pooled) {
  int row = blockIdx.x; int n = row / BB, b = row % BB;
  int lane = threadIdx.x; // 64
  __shared__ float o_s[T_INC][HH];
  for (int t=0;t<T_INC;t++)
    for (int k=lane;k<HH;k+=64)
      o_s[t][k] = outs[(((size_t)t*NN+n)*BB+b)*HH + k];
  __syncthreads();
  float wc = wlc[lane];
  float ab = attb[lane];
  float logit[T_INC];
  for (int t=0;t<T_INC;t++) {
    float acc = ab;
    const float* wr = attW + (size_t)lane*HH;
    for (int k=0;k<HH;k++) acc += wr[k]*o_s[t][k];
    logit[t] = fmaxf(acc, 0.f)*wc;
  }
  for (int off=32; off; off>>=1)
    for (int t=0;t<T_INC;t++) logit[t] += __shfl_xor(logit[t], off, 64);
  float mx = -1e30f;
  for (int t=0;t<T_INC;t++) mx = fmaxf(mx, logit[t]);
  float s = 0.f;
  for (int t=0;t<T_INC;t++) { logit[t] = expf(logit[t]-mx); s += logit[t]; }
  float inv = 1.f/s;
  for (int k=lane;k<HH;k+=64) {
    float acc = 0.f;
    for (int t=0;t<T_INC;t++) acc += o_s[t][k]*logit[t];
    pooled[((size_t)b*NN+n)*HH + k] = acc*inv;
  }
}

// ---------------- key/query projections ----------------
__global__ void k_keyquery(const float* __restrict__ pooled, const float* __restrict__ wkey,
                           const float* __restrict__ wqry, float* __restrict__ keym,
                           float* __restrict__ qm) {
  int bn = blockIdx.x; int lane = threadIdx.x; // 64
  __shared__ float p_s[HH];
  p_s[lane] = pooled[(size_t)bn*HH + lane];
  p_s[lane+64] = pooled[(size_t)bn*HH + lane + 64];
  __syncthreads();
  float ka = 0.f, qa = 0.f;
  for (int k=0;k<HH;k++) {
    float pv = p_s[k];
    ka += pv*wkey[(size_t)k*DHALF + lane];
    qa += pv*wqry[(size_t)k*DHALF + lane];
  }
  keym[(size_t)bn*DHALF + lane] = ka;
  qm[(size_t)bn*DHALF + lane] = qa;
}

// ---------------- attention row -> softmax -> topk -> adj row + rowsum ----------------
__global__ void k_attn_row(const float* __restrict__ keym, const float* __restrict__ qm,
                           const int* __restrict__ topkp, float* __restrict__ adj,
                           float* __restrict__ rowsum) {
  int bn = blockIdx.x; int b = bn / NN; int n = bn % NN;
  int tid = threadIdx.x; // 256
  __shared__ float key_s[DHALF];
  __shared__ float attv[256];
  __shared__ float red[256];
  __shared__ int redi[256];
  if (tid < DHALF) key_s[tid] = keym[(size_t)bn*DHALF + tid];
  __syncthreads();
  float sc = -1e30f;
  if (tid < NN) {
    float a = 0.f;
    const float* qrow = qm + ((size_t)b*NN + tid)*DHALF;
    for (int k=0;k<DHALF;k++) a += key_s[k]*qrow[k];
    sc = a * INV_SQRT_H;
  }
  red[tid] = sc; __syncthreads();
  for (int s=128;s>0;s>>=1){ if (tid<s) red[tid]=fmaxf(red[tid],red[tid+s]); __syncthreads(); }
  float mx = red[0]; __syncthreads();
  float e = (tid<NN) ? expf(sc-mx) : 0.f;
  red[tid] = e; __syncthreads();
  for (int s=128;s>0;s>>=1){ if (tid<s) red[tid]+=red[tid+s]; __syncthreads(); }
  float inv = 1.f/red[0]; __syncthreads();
  float av = e*inv;
  attv[tid] = (tid<NN) ? av : -1e30f;
  __syncthreads();
  int Ks = topkp[0]; if (Ks > NN) Ks = NN;
  float kth = -1e30f;
  for (int it=0; it<Ks; it++) {
    red[tid] = attv[tid]; redi[tid] = tid; __syncthreads();
    for (int s=128;s>0;s>>=1){
      if (tid<s && red[tid+s] > red[tid]) { red[tid]=red[tid+s]; redi[tid]=redi[tid+s]; }
      __syncthreads();
    }
    kth = red[0];
    if (tid==0) attv[redi[0]] = -1e30f;
    __syncthreads();
  }
  float aout = 0.f;
  if (tid < NN) {
    aout = (av >= kth) ? av : 0.f;
    if (tid == n) aout += 1.f;
    adj[((size_t)b*NN+n)*NN + tid] = aout;
  }
  red[tid] = aout; __syncthreads();
  for (int s=128;s>0;s>>=1){ if (tid<s) red[tid]+=red[tid+s]; __syncthreads(); }
  if (tid==0) rowsum[bn] = red[0];
}

// ---------------- column sums of adj ----------------
__global__ void k_colsum(const float* __restrict__ adj, float* __restrict__ cs) {
  int b = blockIdx.x;
  for (int j=threadIdx.x; j<NN; j+=blockDim.x) {
    float s = 0.f;
    for (int i=0;i<NN;i++) s += adj[((size_t)b*NN+i)*NN + j];
    cs[(size_t)b*NN + j] = s;
  }
}

// ---------------- fused gconv via MFMA: concat + 4 hops per (chunk,batch) ------------
// LDS: X0 panel + XT panel in B-frag layout, hi/lo bf16 (4 x 14,336 B = 57KB).
// A-operand = pre-shuffled S fragments (global, L2-resident). X planes packed u32.
__global__ __launch_bounds__(256) void k_gconv_mfma(
    const float* __restrict__ x, int bs, int ns, int din,
    const float* __restrict__ h, const float* __restrict__ ru,
    const __hip_bfloat16* __restrict__ SFH, const __hip_bfloat16* __restrict__ SFL,
    uint32_t* __restrict__ XP, int d) {
  extern __shared__ char ldsc[];
  ushort* X0H = (ushort*)ldsc;          // [KT2*QT][64][8]
  ushort* X0L = X0H + PANEL_E;
  ushort* XTH = X0L + PANEL_E;
  ushort* XTL = XTH + PANEL_E;
  int c0 = blockIdx.x*CHUNK;
  int b  = blockIdx.y;
  int tid = threadIdx.x;
  int l = tid & 63, wid = tid >> 6;     // 4 waves

  // zero all panels (covers pad rows 200..223 and XT rows never written)
  { uint4 z = make_uint4(0,0,0,0);
    uint4* p = (uint4*)ldsc;
    for (int i = tid; i < GCONV_LDS/16; i += 256) p[i] = z; }
  __syncthreads();

  // concat -> X0 frag panel + global plane m=0
  for (int i = tid; i < NN*CHUNK; i += 256) {
    int n = i >> 5, cc = i & 31;
    int c = c0 + cc;
    float v = 0.f;
    if (c < din) {
      v = x[(size_t)b*bs + (size_t)n*ns + c];
    } else if (c < d) {
      int k = c - din;
      v = h[((size_t)(b*NN+n))*HH + k];
      if (ru) v *= ru[(size_t)(b*NN+n)*256 + k];
    }
    uint32_t hi, lo; splitbf(v, hi, lo);
    int kt = n >> 5, kr = n & 31;
    int ln = ((kr>>3)<<4) | (cc & 15), jj = kr & 7, q = cc >> 4;
    int fa = ((kt*QT + q)*64 + ln)*8 + jj;
    X0H[fa] = (ushort)hi; X0L[fa] = (ushort)lo;
    XP[(size_t)(b*NN+n)*XROW + c] = hi | (lo << 16);
  }
  __syncthreads();

  // 4 phases: (S1 hop1)->XT,m1 ; (S1 cheb XT)->m2 ; (S2 hop1)->XT,m3 ; (S2 cheb XT)->m4
  for (int ph = 0; ph < 4; ph++) {
    int side = ph >> 1, cheb = ph & 1;
    const ushort* BH = cheb ? XTH : X0H;
    const ushort* BL = cheb ? XTL : X0L;
    const __hip_bfloat16* AH = SFH + (size_t)(side*BB + b)*SFRAG_PER_B;
    const __hip_bfloat16* AL = SFL + (size_t)(side*BB + b)*SFRAG_PER_B;
    int mout = 1 + ph;
    for (int rt = wid; rt < RT2; rt += 4) {
      f32x4 acc[QT];
      #pragma unroll
      for (int q=0;q<QT;q++) acc[q] = (f32x4){0.f,0.f,0.f,0.f};
      for (int kt = 0; kt < KT2; kt++) {
        size_t aoff = ((size_t)(rt*KT2+kt)*64 + l)*8;
        bf16x8 ah = *(const bf16x8*)(AH + aoff);
        bf16x8 al = *(const bf16x8*)(AL + aoff);
        #pragma unroll
        for (int q=0;q<QT;q++) {
          int boff = ((kt*QT+q)*64 + l)*8;
          bf16x8 bh = *(const bf16x8*)(BH + boff);
          bf16x8 bl = *(const bf16x8*)(BL + boff);
          acc[q] = __builtin_amdgcn_mfma_f32_16x16x32_bf16(ah, bl, acc[q], 0, 0, 0);
          acc[q] = __builtin_amdgcn_mfma_f32_16x16x32_bf16(al, bh, acc[q], 0, 0, 0);
          acc[q] = __builtin_amdgcn_mfma_f32_16x16x32_bf16(ah, bh, acc[q], 0, 0, 0);
        }
      }
      int colb = l & 15;
      #pragma unroll
      for (int q=0;q<QT;q++) {
        int cc = q*16 + colb;
        #pragma unroll
        for (int r=0;r<4;r++) {
          int n = rt*16 + ((l>>4)<<2) + r;
          float v = acc[q][r];
          int kt2 = n >> 5, kr = n & 31;
          int ln = ((kr>>3)<<4) | colb, jj = kr & 7;
          int fa = ((kt2*QT + q)*64 + ln)*8 + jj;
          if (cheb) {
            uint32_t h2 = X0H[fa], l2 = X0L[fa];
            v = 2.f*v - (bfu(h2) + bfu(l2));
          }
          uint32_t hi, lo; splitbf(v, hi, lo);
          if (!cheb) { XTH[fa] = (ushort)hi; XTL[fa] = (ushort)lo; }
          if (n < NN)
            XP[(size_t)mout*MSTRIDE + (size_t)(b*NN+n)*XROW + c0 + cc] = hi | (lo << 16);
        }
      }
    }
    __syncthreads();
  }
}

// ---------------- dense via split-bf16 MFMA, LDS-staged A: Y = act( sum Xm@Wm + b ) --
// PATH 0 (gate):   RU[row*256+col] = sigmoid(v)        (OUT=256)
// PATH 1 (cand):   hnew = u*h + (1-u)*tanh(v); optional fused proj (pW != null)
template<int OUT, int PATH>
__global__ __launch_bounds__(256) void k_dense_mfma(
    const uint32_t* __restrict__ XP,
    const __hip_bfloat16* __restrict__ Wfh, const __hip_bfloat16* __restrict__ Wfl,
    const float* __restrict__ bias, int d_pad,
    float* __restrict__ RU, const float* __restrict__ h, float* __restrict__ hnew,
    const float* __restrict__ pW, const float* __restrict__ pb,
    float* __restrict__ out, float* __restrict__ decx, int t) {
  __shared__ ushort SA[2*32*256];       // hi tile [32][256] + lo tile, XOR-swizzled; 32KB
  ushort* SAh = SA;
  ushort* SAl = SA + 32*256;
  int tid = threadIdx.x;
  int w = tid >> 6, l = tid & 63;
  int rblk = blockIdx.x*32;
  int rbase = (w&1)*16;                 // relative row base
  int cbase = blockIdx.y*128 + (w>>1)*64;
  const int NT = OUT >> 4;
  int KT = d_pad >> 5;
  f32x4 acc[4];
  #pragma unroll
  for (int q=0;q<4;q++) acc[q] = (f32x4){0.f,0.f,0.f,0.f};
  size_t boff = (((size_t)(cbase>>4))*64 + l)*8;
  int ngrp = d_pad >> 3;                // 8-elem groups per row
  for (int m=0;m<5;m++) {
    __syncthreads();
    // stage plane m tile [32][d_pad]: coalesced dwordx4 pairs + unpack hi/lo
    for (int i = tid; i < 32*ngrp; i += 256) {
      int r = i / ngrp, cg = i % ngrp;
      const uint32_t* gp = XP + (size_t)m*MSTRIDE + (size_t)(rblk+r)*XROW + cg*8;
      uint4 p0 = *(const uint4*)gp;
      uint4 p1 = *(const uint4*)(gp+4);
      uint4 hv, lv;
      hv.x = (p0.x & 0xffffu) | (p0.y << 16);
      hv.y = (p0.z & 0xffffu) | (p0.w << 16);
      hv.z = (p1.x & 0xffffu) | (p1.y << 16);
      hv.w = (p1.z & 0xffffu) | (p1.w << 16);
      lv.x = (p0.x >> 16) | (p0.y & 0xffff0000u);
      lv.y = (p0.z >> 16) | (p0.w & 0xffff0000u);
      lv.z = (p1.x >> 16) | (p1.y & 0xffff0000u);
      lv.w = (p1.z >> 16) | (p1.w & 0xffff0000u);
      uint32_t bo2 = ((uint32_t)(r*256 + cg*8)*2) ^ ((uint32_t)(r&7)<<4);
      *(uint4*)((char*)SAh + bo2) = hv;
      *(uint4*)((char*)SAl + bo2) = lv;
    }
    __syncthreads();
    for (int kt=0; kt<KT; kt++) {
      int rr = rbase + (l & 15);
      uint32_t fb = ((uint32_t)(rr*256 + kt*32 + (l>>4)*8)*2) ^ ((uint32_t)(rr&7)<<4);
      bf16x8 ah = *(const bf16x8*)((const char*)SAh + fb);
      bf16x8 al = *(const bf16x8*)((const char*)SAl + fb);
      size_t bo = boff + ((size_t)(m*KT + kt)*NT)*512;
      #pragma unroll
      for (int q=0;q<4;q++) {
        bf16x8 bh = *(const bf16x8*)(Wfh + bo + (size_t)q*512);
        bf16x8 bl = *(const bf16x8*)(Wfl + bo + (size_t)q*512);
        acc[q] = __builtin_amdgcn_mfma_f32_16x16x32_bf16(ah, bl, acc[q], 0, 0, 0);
        acc[q] = __builtin_amdgcn_mfma_f32_16x16x32_bf16(al, bh, acc[q], 0, 0, 0);
        acc[q] = __builtin_amdgcn_mfma_f32_16x16x32_bf16(ah, bh, acc[q], 0, 0, 0);
      }
    }
  }
  bool doproj = (PATH==1) && (pW != nullptr);
  if (doproj) __syncthreads();          // all waves done with SA before PH reuse
  float* PH = (float*)SA;               // [32][128] tile for proj (16KB)
  int drow0 = rbase + ((l>>4)<<2);
  int col0 = l & 15;
  #pragma unroll
  for (int q=0;q<4;q++) {
    int col = cbase + q*16 + col0;
    float bv = bias[col];
    #pragma unroll
    for (int r=0;r<4;r++) {
      int rowrel = drow0 + r;
      int row = rblk + rowrel;
      float v = acc[q][r] + bv;
      if (PATH==0) {
        RU[(size_t)row*256 + col] = sigmf(v);
      } else {
        float c = tanhf(v);
        float u = RU[(size_t)row*256 + 128 + col];
        float hv = u*h[(size_t)row*HH + col] + (1.f-u)*c;
        hnew[(size_t)row*HH + col] = hv;
        if (doproj) PH[rowrel*HH + col] = hv;
      }
    }
  }
  if (doproj) {
    __syncthreads();
    int rowrel = tid >> 3;              // 0..31
    int sub = tid & 7;
    float s = 0.f;
    const float* ph = PH + rowrel*HH + sub*16;
    #pragma unroll
    for (int c=0;c<16;c++) s += ph[c]*pW[sub*16 + c];
    s += __shfl_xor(s, 1, 64);
    s += __shfl_xor(s, 2, 64);
    s += __shfl_xor(s, 4, 64);
    if (sub == 0) {
      float pv = s + pb[0];
      int gr = rblk + rowrel;
      out[(size_t)t*NB + gr] = pv;
      decx[gr] = pv;
    }
  }
}

extern "C" void kernel_launch(void* const* d_in, const int* in_sizes, int n_in,
                              void* d_out, int out_size, void* d_ws, size_t ws_size,
                              hipStream_t stream) {
  const float* enc_in = (const float*)d_in[0];
  const float* gWih = (const float*)d_in[2];
  const float* gWhh = (const float*)d_in[3];
  const float* gbih = (const float*)d_in[4];
  const float* gbhh = (const float*)d_in[5];
  const float* attW = (const float*)d_in[6];
  const float* attb = (const float*)d_in[7];
  const float* wlc  = (const float*)d_in[8];
  const float* wkey = (const float*)d_in[9];
  const float* wqry = (const float*)d_in[10];
  const float* cWg[4] = {(const float*)d_in[11],(const float*)d_in[15],(const float*)d_in[19],(const float*)d_in[23]};
  const float* cbg[4] = {(const float*)d_in[12],(const float*)d_in[16],(const float*)d_in[20],(const float*)d_in[24]};
  const float* cWc[4] = {(const float*)d_in[13],(const float*)d_in[17],(const float*)d_in[21],(const float*)d_in[25]};
  const float* cbc[4] = {(const float*)d_in[14],(const float*)d_in[18],(const float*)d_in[22],(const float*)d_in[26]};
  const float* pW = (const float*)d_in[27];
  const float* pb = (const float*)d_in[28];
  const int* topkp = (const int*)d_in[29];
  float* out = (float*)d_out;

  // d_pad per param set (multiple of CHUNK): 0=enc l0 (d=130), 1=enc l1 (256),
  // 2=dec l0 (129), 3=dec l1 (256)
  const int d_full[4] = {130, 256, 129, 256};
  const int d_padv[4] = {192, 256, 192, 256};

  float* ws = (float*)d_ws;
  size_t off = 0;
  auto alloc = [&](size_t n) { float* p = ws + off; off += (n + 255) & ~(size_t)255; return p; };

  // ---- persistent allocations ----
  float* RS   = alloc(NB);
  float* CS   = alloc(NB);
  float* RU   = alloc((size_t)NB*256);
  float* H0A  = alloc((size_t)NB*HH);
  float* H0B  = alloc((size_t)NB*HH);
  float* H1A  = alloc((size_t)NB*HH);
  float* H1B  = alloc((size_t)NB*HH);
  float* DECX = alloc(NB);
  float* WHHT = alloc((size_t)3*HH*HH);
  __hip_bfloat16* SFH = (__hip_bfloat16*)alloc((size_t)2*BB*SFRAG_PER_B/2);
  __hip_bfloat16* SFL = (__hip_bfloat16*)alloc((size_t)2*BB*SFRAG_PER_B/2);
  __hip_bfloat16 *WGFh[4], *WGFl[4], *WCFh[4], *WCFl[4];
  for (int p=0;p<4;p++) {
    WGFh[p] = (__hip_bfloat16*)alloc((size_t)5*d_padv[p]*256/2);
    WGFl[p] = (__hip_bfloat16*)alloc((size_t)5*d_padv[p]*256/2);
    WCFh[p] = (__hip_bfloat16*)alloc((size_t)5*d_padv[p]*128/2);
    WCFl[p] = (__hip_bfloat16*)alloc((size_t)5*d_padv[p]*128/2);
  }

  // ---- union region: supports-phase scratch OR cell-phase packed X planes ----
  const size_t SUP_SZ = (size_t)T_INC*NN*BB*HH   // OUTS
                      + (size_t)NB*HH            // HGRU
                      + (size_t)NB*HH            // POOL
                      + (size_t)NB*DHALF*2       // KEYM,QMM
                      + (size_t)BB*NN*NN + 4096; // ADJ + pad
  const size_t CELL_SZ = 5*MSTRIDE + 4096;       // XP (u32 per elem)
  float* UNION = alloc(SUP_SZ > CELL_SZ ? SUP_SZ : CELL_SZ);
  // supports view
  float* OUTS = UNION;
  float* HGRU = OUTS + (size_t)T_INC*NN*BB*HH;
  float* POOL = HGRU + (size_t)NB*HH;
  float* KEYM = POOL + (size_t)NB*HH;
  float* QMM  = KEYM + (size_t)NB*DHALF;
  float* ADJ  = QMM  + (size_t)NB*DHALF;
  // cells view
  uint32_t* XP = (uint32_t*)UNION;               // 5 packed planes

  if (off*sizeof(float) > ws_size) return;

  hipMemsetAsync(HGRU, 0, (size_t)NB*HH*sizeof(float), stream);
  hipMemsetAsync(H0A, 0, (size_t)NB*HH*sizeof(float), stream);
  hipMemsetAsync(H1A, 0, (size_t)NB*HH*sizeof(float), stream);
  hipMemsetAsync(DECX, 0, (size_t)NB*sizeof(float), stream);

  // ---- prep: weight transforms ----
  k_whhT<<<(3*HH*HH+255)/256, 256, 0, stream>>>(gWhh, WHHT);
  for (int p=0;p<4;p++) {
    int tg = 5*d_padv[p]*256;
    k_wshuf<<<(tg+255)/256, 256, 0, stream>>>(cWg[p], WGFh[p], WGFl[p], d_full[p], d_padv[p], 256);
    int tc = 5*d_padv[p]*128;
    k_wshuf<<<(tc+255)/256, 256, 0, stream>>>(cWc[p], WCFh[p], WCFl[p], d_full[p], d_padv[p], 128);
  }

  // ---- supports ----
  for (int t=0;t<T_INC;t++)
    k_gru_step<<<NB/4, 512, 0, stream>>>(enc_in, gWih, WHHT, gbih, gbhh, HGRU, OUTS, t);
  k_att_pool<<<NB, 64, 0, stream>>>(OUTS, attW, attb, wlc, POOL);
  k_keyquery<<<NB, 64, 0, stream>>>(POOL, wkey, wqry, KEYM, QMM);
  k_attn_row<<<NB, 256, 0, stream>>>(KEYM, QMM, topkp, ADJ, RS);
  k_colsum<<<BB, 256, 0, stream>>>(ADJ, CS);
  { int tot = 2*BB*208*224;
    k_sshuf<<<(tot+255)/256, 256, 0, stream>>>(ADJ, RS, CS, SFH, SFL); }

  auto gconv = [&](const float* x, int bs, int ns, int din, const float* hcur,
                   const float* ru, int pidx) {
    int d = d_full[pidx], dp = d_padv[pidx];
    dim3 gg(dp/CHUNK, BB);
    k_gconv_mfma<<<gg, 256, GCONV_LDS, stream>>>(
        x, bs, ns, din, hcur, ru, SFH, SFL, XP, d);
  };

  auto cell = [&](const float* x, int bs, int ns, int din,
                  float** hcur, float** halt, int pidx, int t) {
    int dp = d_padv[pidx];
    // gate
    gconv(x, bs, ns, din, *hcur, nullptr, pidx);
    k_dense_mfma<256,0><<<dim3(NB/32,2),256,0,stream>>>(
        XP, WGFh[pidx], WGFl[pidx], cbg[pidx], dp, RU, nullptr, nullptr,
        nullptr, nullptr, nullptr, nullptr, 0);
    // candidate (+fused hnew, + fused proj on decoder layer 1)
    gconv(x, bs, ns, din, *hcur, RU, pidx);
    const float* ppW = (pidx == 3) ? pW : nullptr;
    k_dense_mfma<128,1><<<dim3(NB/32,1),256,0,stream>>>(
        XP, WCFh[pidx], WCFl[pidx], cbc[pidx], dp, RU, *hcur, *halt,
        ppW, pb, out, DECX, t);
    float* tswp = *hcur; *hcur = *halt; *halt = tswp;
  };

  float* h0cur = H0A; float* h0alt = H0B;
  float* h1cur = H1A; float* h1alt = H1B;

  for (int t=0;t<T_INC;t++) {
    cell(enc_in + (size_t)t*NN*DIN0, T_INC*NN*DIN0, DIN0, DIN0, &h0cur, &h0alt, 0, 0);
    cell(h0cur, NN*HH, HH, HH, &h1cur, &h1alt, 1, 0);
  }
  for (int t=0;t<T_OUTC;t++) {
    cell(DECX, NN, 1, 1, &h0cur, &h0alt, 2, t);
    cell(h0cur, NN*HH, HH, HH, &h1cur, &h1alt, 3, t);
  }
}

// Round 10
// 9072.395 us; speedup vs baseline: 5.4862x; 1.2817x over previous
//
#include <hip/hip_runtime.h>
#include <hip/hip_bf16.h>
#include <math.h>

#define BB 32
#define T_INC 12
#define T_OUTC 12
#define NN 200
#define DIN0 2
#define HH 128
#define DHALF 64
#define NB (NN*BB)
#define XROW 256                      // fixed row stride (elems) for X planes
#define MSTRIDE ((size_t)NB*XROW)     // per-m stride in elems (u32 each: hi|lo<<16)
#define CHUNK 32                      // column chunk per gconv block
#define QT 2                          // 16-col q-tiles per chunk
#define KT2 7                         // S k-tiles: 224 = 7*32
#define RT2 13                        // S row-tiles: 208 = 13*16
#define SFRAG_PER_B ((size_t)RT2*KT2*64*8)   // elems per (mat,b)
#define PANEL_E (KT2*QT*64*8)         // 7168 bf16 per LDS panel
#define GCONV_LDS (4*PANEL_E*2)       // 57,344 B
#define INV_SQRT_H 0.08838834764831845f

typedef __attribute__((ext_vector_type(8))) short bf16x8;
typedef __attribute__((ext_vector_type(4))) float f32x4;

__device__ __forceinline__ float sigmf(float x){ return 1.f/(1.f+expf(-x)); }
__device__ __forceinline__ float bfu(uint32_t b){ union{uint32_t u;float f;}v; v.u=b<<16; return v.f; }
__device__ __forceinline__ uint32_t fbf(float f){ union{float f2;uint32_t u;}v; v.f2=f; return (v.u + 0x7fffu + ((v.u>>16)&1u))>>16; }
// split v into bf16 hi + bf16 lo (v ~= hi + lo to ~17 mantissa bits)
__device__ __forceinline__ void splitbf(float v, uint32_t& hi, uint32_t& lo){
  hi = fbf(v);
  lo = fbf(v - bfu(hi));
}

// ---------------- prep: transpose Whh (3H x H) -> (H x 3H) ----------------
__global__ void k_whhT(const float* __restrict__ Whh, float* __restrict__ WT) {
  int idx = blockIdx.x*256 + threadIdx.x;
  if (idx >= 3*HH*HH) return;
  int i3 = idx / HH; int k = idx % HH;
  WT[(size_t)k*(3*HH) + i3] = Whh[idx];
}

// ---------------- prep: shuffle dense weights into MFMA B-fragment layout, hi/lo ----
__global__ void k_wshuf(const float* __restrict__ W, __hip_bfloat16* __restrict__ Wfh,
                        __hip_bfloat16* __restrict__ Wfl, int d, int d_pad, int OUT) {
  int idx = blockIdx.x*256 + threadIdx.x;
  int total = 5*d_pad*OUT;
  if (idx >= total) return;
  int o = idx % OUT; int tmp = idx / OUT; int k = tmp % d_pad; int m = tmp / d_pad;
  float v = (k < d) ? W[((size_t)k*5 + m)*OUT + o] : 0.f;
  int kt = k >> 5, kr = k & 31;
  int lane = ((kr>>3)<<4) | (o & 15);
  int j = kr & 7;
  int nt = o >> 4;
  int KT = d_pad >> 5, NT = OUT >> 4;
  size_t addr = ((((size_t)m*KT + kt)*NT + nt)*64 + (size_t)lane)*8 + j;
  uint32_t hi, lo; splitbf(v, hi, lo);
  Wfh[addr] = *(__hip_bfloat16*)&hi;
  Wfl[addr] = *(__hip_bfloat16*)&lo;
}

// ---------------- prep: shuffle S1/S2 (dense, from adj) into A-frag layout, hi/lo ----
// s1[n][j] = adj[j][n]/rs[j] ; s2[n][j] = adj[n][j]/cs[j] ; padded to 208x224
__global__ void k_sshuf(const float* __restrict__ adj, const float* __restrict__ rs,
                        const float* __restrict__ cs,
                        __hip_bfloat16* __restrict__ SFH, __hip_bfloat16* __restrict__ SFL) {
  const int PER_B = 208*224;
  int idx = blockIdx.x*256 + threadIdx.x;
  if (idx >= 2*BB*PER_B) return;
  int e = idx % PER_B; int t2 = idx / PER_B; int b = t2 % BB; int mat = t2 / BB;
  int n = e / 224; int j = e % 224;
  float v = 0.f;
  if (n < NN && j < NN) {
    if (mat == 0) v = adj[((size_t)b*NN + j)*NN + n] / rs[(size_t)b*NN + j];
    else          v = adj[((size_t)b*NN + n)*NN + j] / cs[(size_t)b*NN + j];
  }
  int rt = n >> 4, rr = n & 15, kt = j >> 5, kr = j & 31;
  int lane = ((kr >> 3) << 4) | rr;
  int jj = kr & 7;
  size_t addr = ((size_t)(mat*BB + b)*RT2*KT2 + (size_t)(rt*KT2 + kt))*512
              + (size_t)lane*8 + jj;
  uint32_t hi, lo; splitbf(v, hi, lo);
  SFH[addr] = *(__hip_bfloat16*)&hi;
  SFL[addr] = *(__hip_bfloat16*)&lo;
}

// ---------------- GRU, all 12 steps fused (recurrence is row-independent) ----------
__global__ __launch_bounds__(512) void k_gru_all(
    const float* __restrict__ enc_in, const float* __restrict__ Wih,
    const float* __restrict__ WhhT, const float* __restrict__ bih,
    const float* __restrict__ bhh, float* __restrict__ outs) {
  int row0 = blockIdx.x * 4;
  int tid = threadIdx.x;
  int rr = tid >> 7;
  int i = tid & 127;
  int row = row0 + rr;
  int n = row / BB, b = row % BB;
  __shared__ float hs[4][HH];
  hs[rr][i] = 0.f;
  float wi0 = Wih[(0*HH+i)*2+0], wi1 = Wih[(0*HH+i)*2+1];
  float wz0 = Wih[(1*HH+i)*2+0], wz1 = Wih[(1*HH+i)*2+1];
  float wg0 = Wih[(2*HH+i)*2+0], wg1 = Wih[(2*HH+i)*2+1];
  float bi = bih[i], bz = bih[HH+i], bg = bih[2*HH+i];
  float bhr = bhh[i], bhz = bhh[HH+i], bhg = bhh[2*HH+i];
  for (int t=0;t<T_INC;t++) {
    __syncthreads();
    float x0 = enc_in[(((size_t)b*T_INC + t)*NN + n)*DIN0 + 0];
    float x1 = enc_in[(((size_t)b*T_INC + t)*NN + n)*DIN0 + 1];
    float ir = wi0*x0 + wi1*x1 + bi;
    float iz = wz0*x0 + wz1*x1 + bz;
    float ig = wg0*x0 + wg1*x1 + bg;
    float hr = bhr, hz = bhz, hg = bhg;
    for (int k=0;k<HH;k++) {
      float hv = hs[rr][k];
      const float* wr = WhhT + (size_t)k*(3*HH);
      hr += wr[i]*hv; hz += wr[i+128]*hv; hg += wr[i+256]*hv;
    }
    float r = sigmf(ir+hr);
    float z = sigmf(iz+hz);
    float nn2 = tanhf(ig + r*hg);
    float hn = (1.f-z)*nn2 + z*hs[rr][i];
    __syncthreads();
    hs[rr][i] = hn;
    outs[(((size_t)t*NN+n)*BB+b)*HH + i] = hn;
  }
}

// ---------------- length-attention pooling (256 thr, LDS-staged attW) ---------------
__global__ __launch_bounds__(256) void k_att_pool(
    const float* __restrict__ outs, const float* __restrict__ attW,
    const float* __restrict__ attb, const float* __restrict__ wlc,
    float* __restrict__ pooled) {
  int row = blockIdx.x; int n = row / BB, b = row % BB;
  int tid = threadIdx.x;
  __shared__ float o_s[T_INC][HH];
  __shared__ float aw[DHALF][HH+1];    // +1 pad: bank (d+k)%32, 2-way max (free)
  __shared__ float pt[T_INC];
  for (int i = tid; i < T_INC*HH; i += 256) {
    int t = i >> 7, k = i & 127;
    o_s[t][k] = outs[(((size_t)t*NN+n)*BB+b)*HH + k];
  }
  for (int i = tid; i < DHALF*HH; i += 256) {
    int d2 = i >> 7, k = i & 127;
    aw[d2][k] = attW[(size_t)d2*HH + k];
  }
  __syncthreads();
  int d = tid & 63, tq = tid >> 6;     // wave tq handles t = tq, tq+4, tq+8
  float ab = attb[d], wc = wlc[d];
  float part[3];
  #pragma unroll
  for (int j=0;j<3;j++) {
    int t = tq + j*4;
    float acc = ab;
    for (int k=0;k<HH;k++) acc += aw[d][k]*o_s[t][k];
    part[j] = fmaxf(acc, 0.f)*wc;
  }
  for (int off=32; off; off>>=1)
    #pragma unroll
    for (int j=0;j<3;j++) part[j] += __shfl_xor(part[j], off, 64);
  if (d == 0) { pt[tq] = part[0]; pt[tq+4] = part[1]; pt[tq+8] = part[2]; }
  __syncthreads();
  float mx = -1e30f;
  for (int t=0;t<T_INC;t++) mx = fmaxf(mx, pt[t]);
  float e[T_INC]; float s = 0.f;
  for (int t=0;t<T_INC;t++) { e[t] = expf(pt[t]-mx); s += e[t]; }
  float inv = 1.f/s;
  for (int k=tid;k<HH;k+=256) {
    float acc = 0.f;
    for (int t=0;t<T_INC;t++) acc += o_s[t][k]*e[t];
    pooled[((size_t)b*NN+n)*HH + k] = acc*inv;
  }
}

// ---------------- key/query projections ----------------
__global__ void k_keyquery(const float* __restrict__ pooled, const float* __restrict__ wkey,
                           const float* __restrict__ wqry, float* __restrict__ keym,
                           float* __restrict__ qm) {
  int bn = blockIdx.x; int lane = threadIdx.x; // 64
  __shared__ float p_s[HH];
  p_s[lane] = pooled[(size_t)bn*HH + lane];
  p_s[lane+64] = pooled[(size_t)bn*HH + lane + 64];
  __syncthreads();
  float ka = 0.f, qa = 0.f;
  for (int k=0;k<HH;k++) {
    float pv = p_s[k];
    ka += pv*wkey[(size_t)k*DHALF + lane];
    qa += pv*wqry[(size_t)k*DHALF + lane];
  }
  keym[(size_t)bn*DHALF + lane] = ka;
  qm[(size_t)bn*DHALF + lane] = qa;
}

// ---------------- attention row -> softmax -> topk -> adj row + rowsum ----------------
__global__ void k_attn_row(const float* __restrict__ keym, const float* __restrict__ qm,
                           const int* __restrict__ topkp, float* __restrict__ adj,
                           float* __restrict__ rowsum) {
  int bn = blockIdx.x; int b = bn / NN; int n = bn % NN;
  int tid = threadIdx.x; // 256
  __shared__ float key_s[DHALF];
  __shared__ float attv[256];
  __shared__ float red[256];
  __shared__ int redi[256];
  if (tid < DHALF) key_s[tid] = keym[(size_t)bn*DHALF + tid];
  __syncthreads();
  float sc = -1e30f;
  if (tid < NN) {
    float a = 0.f;
    const float* qrow = qm + ((size_t)b*NN + tid)*DHALF;
    for (int k=0;k<DHALF;k++) a += key_s[k]*qrow[k];
    sc = a * INV_SQRT_H;
  }
  red[tid] = sc; __syncthreads();
  for (int s=128;s>0;s>>=1){ if (tid<s) red[tid]=fmaxf(red[tid],red[tid+s]); __syncthreads(); }
  float mx = red[0]; __syncthreads();
  float e = (tid<NN) ? expf(sc-mx) : 0.f;
  red[tid] = e; __syncthreads();
  for (int s=128;s>0;s>>=1){ if (tid<s) red[tid]+=red[tid+s]; __syncthreads(); }
  float inv = 1.f/red[0]; __syncthreads();
  float av = e*inv;
  attv[tid] = (tid<NN) ? av : -1e30f;
  __syncthreads();
  int Ks = topkp[0]; if (Ks > NN) Ks = NN;
  float kth = -1e30f;
  for (int it=0; it<Ks; it++) {
    red[tid] = attv[tid]; redi[tid] = tid; __syncthreads();
    for (int s=128;s>0;s>>=1){
      if (tid<s && red[tid+s] > red[tid]) { red[tid]=red[tid+s]; redi[tid]=redi[tid+s]; }
      __syncthreads();
    }
    kth = red[0];
    if (tid==0) attv[redi[0]] = -1e30f;
    __syncthreads();
  }
  float aout = 0.f;
  if (tid < NN) {
    aout = (av >= kth) ? av : 0.f;
    if (tid == n) aout += 1.f;
    adj[((size_t)b*NN+n)*NN + tid] = aout;
  }
  red[tid] = aout; __syncthreads();
  for (int s=128;s>0;s>>=1){ if (tid<s) red[tid]+=red[tid+s]; __syncthreads(); }
  if (tid==0) rowsum[bn] = red[0];
}

// ---------------- column sums of adj ----------------
__global__ void k_colsum(const float* __restrict__ adj, float* __restrict__ cs) {
  int b = blockIdx.x;
  for (int j=threadIdx.x; j<NN; j+=blockDim.x) {
    float s = 0.f;
    for (int i=0;i<NN;i++) s += adj[((size_t)b*NN+i)*NN + j];
    cs[(size_t)b*NN + j] = s;
  }
}

// ---------------- fused gconv via MFMA: concat + 4 hops per (chunk,batch) ------------
// 8 waves (512 thr) for 2 waves/SIMD latency hiding. LDS: X0+XT frag panels (57KB).
__global__ __launch_bounds__(512) void k_gconv_mfma(
    const float* __restrict__ x, int bs, int ns, int din,
    const float* __restrict__ h, const float* __restrict__ ru,
    const __hip_bfloat16* __restrict__ SFH, const __hip_bfloat16* __restrict__ SFL,
    uint32_t* __restrict__ XP, int d) {
  extern __shared__ char ldsc[];
  ushort* X0H = (ushort*)ldsc;          // [KT2*QT][64][8]
  ushort* X0L = X0H + PANEL_E;
  ushort* XTH = X0L + PANEL_E;
  ushort* XTL = XTH + PANEL_E;
  int c0 = blockIdx.x*CHUNK;
  int b  = blockIdx.y;
  int tid = threadIdx.x;
  int l = tid & 63, wid = tid >> 6;     // 8 waves

  // zero all panels (covers pad rows 200..223 and XT rows never written)
  { uint4 z = make_uint4(0,0,0,0);
    uint4* p = (uint4*)ldsc;
    for (int i = tid; i < GCONV_LDS/16; i += 512) p[i] = z; }
  __syncthreads();

  // concat -> X0 frag panel + global plane m=0
  for (int i = tid; i < NN*CHUNK; i += 512) {
    int n = i >> 5, cc = i & 31;
    int c = c0 + cc;
    float v = 0.f;
    if (c < din) {
      v = x[(size_t)b*bs + (size_t)n*ns + c];
    } else if (c < d) {
      int k = c - din;
      v = h[((size_t)(b*NN+n))*HH + k];
      if (ru) v *= ru[(size_t)(b*NN+n)*256 + k];
    }
    uint32_t hi, lo; splitbf(v, hi, lo);
    int kt = n >> 5, kr = n & 31;
    int ln = ((kr>>3)<<4) | (cc & 15), jj = kr & 7, q = cc >> 4;
    int fa = ((kt*QT + q)*64 + ln)*8 + jj;
    X0H[fa] = (ushort)hi; X0L[fa] = (ushort)lo;
    XP[(size_t)(b*NN+n)*XROW + c] = hi | (lo << 16);
  }
  __syncthreads();

  // 4 phases: (S1 hop1)->XT,m1 ; (S1 cheb XT)->m2 ; (S2 hop1)->XT,m3 ; (S2 cheb XT)->m4
  for (int ph = 0; ph < 4; ph++) {
    int side = ph >> 1, cheb = ph & 1;
    const ushort* BH = cheb ? XTH : X0H;
    const ushort* BL = cheb ? XTL : X0L;
    const __hip_bfloat16* AH = SFH + (size_t)(side*BB + b)*SFRAG_PER_B;
    const __hip_bfloat16* AL = SFL + (size_t)(side*BB + b)*SFRAG_PER_B;
    int mout = 1 + ph;
    for (int rt = wid; rt < RT2; rt += 8) {
      f32x4 acc[QT];
      #pragma unroll
      for (int q=0;q<QT;q++) acc[q] = (f32x4){0.f,0.f,0.f,0.f};
      for (int kt = 0; kt < KT2; kt++) {
        size_t aoff = ((size_t)(rt*KT2+kt)*64 + l)*8;
        bf16x8 ah = *(const bf16x8*)(AH + aoff);
        bf16x8 al = *(const bf16x8*)(AL + aoff);
        #pragma unroll
        for (int q=0;q<QT;q++) {
          int boff = ((kt*QT+q)*64 + l)*8;
          bf16x8 bh = *(const bf16x8*)(BH + boff);
          bf16x8 bl = *(const bf16x8*)(BL + boff);
          acc[q] = __builtin_amdgcn_mfma_f32_16x16x32_bf16(ah, bl, acc[q], 0, 0, 0);
          acc[q] = __builtin_amdgcn_mfma_f32_16x16x32_bf16(al, bh, acc[q], 0, 0, 0);
          acc[q] = __builtin_amdgcn_mfma_f32_16x16x32_bf16(ah, bh, acc[q], 0, 0, 0);
        }
      }
      int colb = l & 15;
      #pragma unroll
      for (int q=0;q<QT;q++) {
        int cc = q*16 + colb;
        #pragma unroll
        for (int r=0;r<4;r++) {
          int n = rt*16 + ((l>>4)<<2) + r;
          float v = acc[q][r];
          int kt2 = n >> 5, kr = n & 31;
          int ln = ((kr>>3)<<4) | colb, jj = kr & 7;
          int fa = ((kt2*QT + q)*64 + ln)*8 + jj;
          if (cheb) {
            uint32_t h2 = X0H[fa], l2 = X0L[fa];
            v = 2.f*v - (bfu(h2) + bfu(l2));
          }
          uint32_t hi, lo; splitbf(v, hi, lo);
          if (!cheb) { XTH[fa] = (ushort)hi; XTL[fa] = (ushort)lo; }
          if (n < NN)
            XP[(size_t)mout*MSTRIDE + (size_t)(b*NN+n)*XROW + c0 + cc] = hi | (lo << 16);
        }
      }
    }
    __syncthreads();
  }
}

// ---------------- dense via split-bf16 MFMA, LDS-staged A: Y = act( sum Xm@Wm + b ) --
// PATH 0 (gate):   RU[row*256+col] = sigmoid(v)        (OUT=256)
// PATH 1 (cand):   hnew = u*h + (1-u)*tanh(v); optional fused proj (pW != null)
template<int OUT, int PATH>
__global__ __launch_bounds__(256) void k_dense_mfma(
    const uint32_t* __restrict__ XP,
    const __hip_bfloat16* __restrict__ Wfh, const __hip_bfloat16* __restrict__ Wfl,
    const float* __restrict__ bias, int d_pad,
    float* __restrict__ RU, const float* __restrict__ h, float* __restrict__ hnew,
    const float* __restrict__ pW, const float* __restrict__ pb,
    float* __restrict__ out, float* __restrict__ decx, int t) {
  __shared__ ushort SA[2*32*256];       // hi tile [32][256] + lo tile, XOR-swizzled; 32KB
  ushort* SAh = SA;
  ushort* SAl = SA + 32*256;
  int tid = threadIdx.x;
  int w = tid >> 6, l = tid & 63;
  int rblk = blockIdx.x*32;
  int rbase = (w&1)*16;                 // relative row base
  int cbase = blockIdx.y*128 + (w>>1)*64;
  const int NT = OUT >> 4;
  int KT = d_pad >> 5;
  f32x4 acc[4];
  #pragma unroll
  for (int q=0;q<4;q++) acc[q] = (f32x4){0.f,0.f,0.f,0.f};
  size_t boff = (((size_t)(cbase>>4))*64 + l)*8;
  int ngrp = d_pad >> 3;                // 8-elem groups per row
  for (int m=0;m<5;m++) {
    __syncthreads();
    // stage plane m tile [32][d_pad]: coalesced dwordx4 pairs + unpack hi/lo
    for (int i = tid; i < 32*ngrp; i += 256) {
      int r = i / ngrp, cg = i % ngrp;
      const uint32_t* gp = XP + (size_t)m*MSTRIDE + (size_t)(rblk+r)*XROW + cg*8;
      uint4 p0 = *(const uint4*)gp;
      uint4 p1 = *(const uint4*)(gp+4);
      uint4 hv, lv;
      hv.x = (p0.x & 0xffffu) | (p0.y << 16);
      hv.y = (p0.z & 0xffffu) | (p0.w << 16);
      hv.z = (p1.x & 0xffffu) | (p1.y << 16);
      hv.w = (p1.z & 0xffffu) | (p1.w << 16);
      lv.x = (p0.x >> 16) | (p0.y & 0xffff0000u);
      lv.y = (p0.z >> 16) | (p0.w & 0xffff0000u);
      lv.z = (p1.x >> 16) | (p1.y & 0xffff0000u);
      lv.w = (p1.z >> 16) | (p1.w & 0xffff0000u);
      uint32_t bo2 = ((uint32_t)(r*256 + cg*8)*2) ^ ((uint32_t)(r&7)<<4);
      *(uint4*)((char*)SAh + bo2) = hv;
      *(uint4*)((char*)SAl + bo2) = lv;
    }
    __syncthreads();
    for (int kt=0; kt<KT; kt++) {
      int rr = rbase + (l & 15);
      uint32_t fb = ((uint32_t)(rr*256 + kt*32 + (l>>4)*8)*2) ^ ((uint32_t)(rr&7)<<4);
      bf16x8 ah = *(const bf16x8*)((const char*)SAh + fb);
      bf16x8 al = *(const bf16x8*)((const char*)SAl + fb);
      size_t bo = boff + ((size_t)(m*KT + kt)*NT)*512;
      #pragma unroll
      for (int q=0;q<4;q++) {
        bf16x8 bh = *(const bf16x8*)(Wfh + bo + (size_t)q*512);
        bf16x8 bl = *(const bf16x8*)(Wfl + bo + (size_t)q*512);
        acc[q] = __builtin_amdgcn_mfma_f32_16x16x32_bf16(ah, bl, acc[q], 0, 0, 0);
        acc[q] = __builtin_amdgcn_mfma_f32_16x16x32_bf16(al, bh, acc[q], 0, 0, 0);
        acc[q] = __builtin_amdgcn_mfma_f32_16x16x32_bf16(ah, bh, acc[q], 0, 0, 0);
      }
    }
  }
  bool doproj = (PATH==1) && (pW != nullptr);
  if (doproj) __syncthreads();          // all waves done with SA before PH reuse
  float* PH = (float*)SA;               // [32][128] tile for proj (16KB)
  int drow0 = rbase + ((l>>4)<<2);
  int col0 = l & 15;
  #pragma unroll
  for (int q=0;q<4;q++) {
    int col = cbase + q*16 + col0;
    float bv = bias[col];
    #pragma unroll
    for (int r=0;r<4;r++) {
      int rowrel = drow0 + r;
      int row = rblk + rowrel;
      float v = acc[q][r] + bv;
      if (PATH==0) {
        RU[(size_t)row*256 + col] = sigmf(v);
      } else {
        float c = tanhf(v);
        float u = RU[(size_t)row*256 + 128 + col];
        float hv = u*h[(size_t)row*HH + col] + (1.f-u)*c;
        hnew[(size_t)row*HH + col] = hv;
        if (doproj) PH[rowrel*HH + col] = hv;
      }
    }
  }
  if (doproj) {
    __syncthreads();
    int rowrel = tid >> 3;              // 0..31
    int sub = tid & 7;
    float s = 0.f;
    const float* ph = PH + rowrel*HH + sub*16;
    #pragma unroll
    for (int c=0;c<16;c++) s += ph[c]*pW[sub*16 + c];
    s += __shfl_xor(s, 1, 64);
    s += __shfl_xor(s, 2, 64);
    s += __shfl_xor(s, 4, 64);
    if (sub == 0) {
      float pv = s + pb[0];
      int gr = rblk + rowrel;
      out[(size_t)t*NB + gr] = pv;
      decx[gr] = pv;
    }
  }
}

extern "C" void kernel_launch(void* const* d_in, const int* in_sizes, int n_in,
                              void* d_out, int out_size, void* d_ws, size_t ws_size,
                              hipStream_t stream) {
  const float* enc_in = (const float*)d_in[0];
  const float* gWih = (const float*)d_in[2];
  const float* gWhh = (const float*)d_in[3];
  const float* gbih = (const float*)d_in[4];
  const float* gbhh = (const float*)d_in[5];
  const float* attW = (const float*)d_in[6];
  const float* attb = (const float*)d_in[7];
  const float* wlc  = (const float*)d_in[8];
  const float* wkey = (const float*)d_in[9];
  const float* wqry = (const float*)d_in[10];
  const float* cWg[4] = {(const float*)d_in[11],(const float*)d_in[15],(const float*)d_in[19],(const float*)d_in[23]};
  const float* cbg[4] = {(const float*)d_in[12],(const float*)d_in[16],(const float*)d_in[20],(const float*)d_in[24]};
  const float* cWc[4] = {(const float*)d_in[13],(const float*)d_in[17],(const float*)d_in[21],(const float*)d_in[25]};
  const float* cbc[4] = {(const float*)d_in[14],(const float*)d_in[18],(const float*)d_in[22],(const float*)d_in[26]};
  const float* pW = (const float*)d_in[27];
  const float* pb = (const float*)d_in[28];
  const int* topkp = (const int*)d_in[29];
  float* out = (float*)d_out;

  // d_pad per param set (multiple of CHUNK): 0=enc l0 (d=130), 1=enc l1 (256),
  // 2=dec l0 (129), 3=dec l1 (256)
  const int d_full[4] = {130, 256, 129, 256};
  const int d_padv[4] = {192, 256, 192, 256};

  float* ws = (float*)d_ws;
  size_t off = 0;
  auto alloc = [&](size_t n) { float* p = ws + off; off += (n + 255) & ~(size_t)255; return p; };

  // ---- persistent allocations ----
  float* RS   = alloc(NB);
  float* CS   = alloc(NB);
  float* RU   = alloc((size_t)NB*256);
  float* H0A  = alloc((size_t)NB*HH);
  float* H0B  = alloc((size_t)NB*HH);
  float* H1A  = alloc((size_t)NB*HH);
  float* H1B  = alloc((size_t)NB*HH);
  float* DECX = alloc(NB);
  float* WHHT = alloc((size_t)3*HH*HH);
  __hip_bfloat16* SFH = (__hip_bfloat16*)alloc((size_t)2*BB*SFRAG_PER_B/2);
  __hip_bfloat16* SFL = (__hip_bfloat16*)alloc((size_t)2*BB*SFRAG_PER_B/2);
  __hip_bfloat16 *WGFh[4], *WGFl[4], *WCFh[4], *WCFl[4];
  for (int p=0;p<4;p++) {
    WGFh[p] = (__hip_bfloat16*)alloc((size_t)5*d_padv[p]*256/2);
    WGFl[p] = (__hip_bfloat16*)alloc((size_t)5*d_padv[p]*256/2);
    WCFh[p] = (__hip_bfloat16*)alloc((size_t)5*d_padv[p]*128/2);
    WCFl[p] = (__hip_bfloat16*)alloc((size_t)5*d_padv[p]*128/2);
  }

  // ---- union region: supports-phase scratch OR cell-phase packed X planes ----
  const size_t SUP_SZ = (size_t)T_INC*NN*BB*HH   // OUTS
                      + (size_t)NB*HH            // POOL
                      + (size_t)NB*DHALF*2       // KEYM,QMM
                      + (size_t)BB*NN*NN + 4096; // ADJ + pad
  const size_t CELL_SZ = 5*MSTRIDE + 4096;       // XP (u32 per elem)
  float* UNION = alloc(SUP_SZ > CELL_SZ ? SUP_SZ : CELL_SZ);
  // supports view
  float* OUTS = UNION;
  float* POOL = OUTS + (size_t)T_INC*NN*BB*HH;
  float* KEYM = POOL + (size_t)NB*HH;
  float* QMM  = KEYM + (size_t)NB*DHALF;
  float* ADJ  = QMM  + (size_t)NB*DHALF;
  // cells view
  uint32_t* XP = (uint32_t*)UNION;               // 5 packed planes

  if (off*sizeof(float) > ws_size) return;

  hipMemsetAsync(H0A, 0, (size_t)NB*HH*sizeof(float), stream);
  hipMemsetAsync(H1A, 0, (size_t)NB*HH*sizeof(float), stream);
  hipMemsetAsync(DECX, 0, (size_t)NB*sizeof(float), stream);

  // ---- prep: weight transforms ----
  k_whhT<<<(3*HH*HH+255)/256, 256, 0, stream>>>(gWhh, WHHT);
  for (int p=0;p<4;p++) {
    int tg = 5*d_padv[p]*256;
    k_wshuf<<<(tg+255)/256, 256, 0, stream>>>(cWg[p], WGFh[p], WGFl[p], d_full[p], d_padv[p], 256);
    int tc = 5*d_padv[p]*128;
    k_wshuf<<<(tc+255)/256, 256, 0, stream>>>(cWc[p], WCFh[p], WCFl[p], d_full[p], d_padv[p], 128);
  }

  // ---- supports ----
  k_gru_all<<<NB/4, 512, 0, stream>>>(enc_in, gWih, WHHT, gbih, gbhh, OUTS);
  k_att_pool<<<NB, 256, 0, stream>>>(OUTS, attW, attb, wlc, POOL);
  k_keyquery<<<NB, 64, 0, stream>>>(POOL, wkey, wqry, KEYM, QMM);
  k_attn_row<<<NB, 256, 0, stream>>>(KEYM, QMM, topkp, ADJ, RS);
  k_colsum<<<BB, 256, 0, stream>>>(ADJ, CS);
  { int tot = 2*BB*208*224;
    k_sshuf<<<(tot+255)/256, 256, 0, stream>>>(ADJ, RS, CS, SFH, SFL); }

  auto gconv = [&](const float* x, int bs, int ns, int din, const float* hcur,
                   const float* ru, int pidx) {
    int d = d_full[pidx], dp = d_padv[pidx];
    dim3 gg(dp/CHUNK, BB);
    k_gconv_mfma<<<gg, 512, GCONV_LDS, stream>>>(
        x, bs, ns, din, hcur, ru, SFH, SFL, XP, d);
  };

  auto cell = [&](const float* x, int bs, int ns, int din,
                  float** hcur, float** halt, int pidx, int t) {
    int dp = d_padv[pidx];
    // gate
    gconv(x, bs, ns, din, *hcur, nullptr, pidx);
    k_dense_mfma<256,0><<<dim3(NB/32,2),256,0,stream>>>(
        XP, WGFh[pidx], WGFl[pidx], cbg[pidx], dp, RU, nullptr, nullptr,
        nullptr, nullptr, nullptr, nullptr, 0);
    // candidate (+fused hnew, + fused proj on decoder layer 1)
    gconv(x, bs, ns, din, *hcur, RU, pidx);
    const float* ppW = (pidx == 3) ? pW : nullptr;
    k_dense_mfma<128,1><<<dim3(NB/32,1),256,0,stream>>>(
        XP, WCFh[pidx], WCFl[pidx], cbc[pidx], dp, RU, *hcur, *halt,
        ppW, pb, out, DECX, t);
    float* tswp = *hcur; *hcur = *halt; *halt = tswp;
  };

  float* h0cur = H0A; float* h0alt = H0B;
  float* h1cur = H1A; float* h1alt = H1B;

  for (int t=0;t<T_INC;t++) {
    cell(enc_in + (size_t)t*NN*DIN0, T_INC*NN*DIN0, DIN0, DIN0, &h0cur, &h0alt, 0, 0);
    cell(h0cur, NN*HH, HH, HH, &h1cur, &h1alt, 1, 0);
  }
  for (int t=0;t<T_OUTC;t++) {
    cell(DECX, NN, 1, 1, &h0cur, &h0alt, 2, t);
    cell(h0cur, NN*HH, HH, HH, &h1cur, &h1alt, 3, t);
  }
}